// Round 2
// baseline (1771.627 us; speedup 1.0000x reference)
//
#include <hip/hip_runtime.h>
#include <cstdint>
#include <cstddef>
#include <math.h>

#define B_ 4
#define T_ 1024
#define D_ 512
#define H_ 8
#define E_ 8
#define F_ 1024
#define NTOK (B_*T_)   // 4096
#define HD   (H_*D_)   // 4096

typedef float f32x4 __attribute__((ext_vector_type(4)));
typedef short bf16x8 __attribute__((ext_vector_type(8)));
typedef _Float16 f16x8 __attribute__((ext_vector_type(8)));
typedef unsigned short us;

union H16 { _Float16 h; unsigned short u; };

__device__ __forceinline__ us f2b(float f){
  union { float f; unsigned u; } v; v.f = f;
  unsigned r = v.u + 0x7fffu + ((v.u >> 16) & 1u);
  return (us)(r >> 16);
}
__device__ __forceinline__ float b2f(us h){
  union { unsigned u; float f; } v; v.u = ((unsigned)h) << 16; return v.f;
}
__device__ __forceinline__ void splitf(float x, us& hi, us& lo){
  H16 a, b;
  a.h = (_Float16)x;
  b.h = (_Float16)(x - (float)a.h);
  hi = a.u; lo = b.u;
}

// ---------------------------------------------------------------------------
// fp16 split GEMM: C[M,N] = A[M,K]*B[N,K]^T with A=Ah+Al, B=Bh+Bl fp16 planes.
// 3-product Markidis (AhBh + AhBl + AlBh) -> ~f32 accuracy.
// 128x128 tile, BK=64, 4 waves, 16x16x32 f16 MFMA, global_load_lds staging.
// EPI: 0 = f32 store to C; 1 = fp16 hi/lo split store to Ch/Cl.
// ---------------------------------------------------------------------------
template<int EPI>
__global__ __launch_bounds__(256, 2) void gemm_split(
    const us* __restrict__ Ah, const us* __restrict__ Al,
    const us* __restrict__ Bh, const us* __restrict__ Bl,
    float* __restrict__ C, us* __restrict__ Ch, us* __restrict__ Cl,
    int M, int N, int K)
{
  __shared__ char sm[65536];
  char* sAh = sm;
  char* sAl = sm + 16384;
  char* sBh = sm + 32768;
  char* sBl = sm + 49152;
  const int tid = threadIdx.x;
  const int m0 = blockIdx.y*128, n0 = blockIdx.x*128;
  const int wid = tid >> 6, lane = tid & 63;
  const int wy = wid >> 1, wx = wid & 1;
  const int r16 = lane & 15, g4 = lane >> 4;

  f32x4 acc[4][4];
  #pragma unroll
  for (int i=0;i<4;i++)
    #pragma unroll
    for(int j=0;j<4;j++) acc[i][j] = (f32x4)0.f;

  const int nkt = K >> 6;
  for (int kt = 0; kt < nkt; ++kt) {
    #pragma unroll
    for (int r = 0; r < 4; ++r) {
      int linear = r*256 + tid;
      int row = linear >> 3, ss = linear & 7;
      int sg = ss ^ (row & 7);
      size_t ga = (size_t)(m0+row)*K + kt*64 + sg*8;
      size_t gb = (size_t)(n0+row)*K + kt*64 + sg*8;
      __builtin_amdgcn_global_load_lds((const __attribute__((address_space(1))) void*)(Ah + ga),
        (__attribute__((address_space(3))) void*)(sAh + linear*16), 16, 0, 0);
      __builtin_amdgcn_global_load_lds((const __attribute__((address_space(1))) void*)(Al + ga),
        (__attribute__((address_space(3))) void*)(sAl + linear*16), 16, 0, 0);
      __builtin_amdgcn_global_load_lds((const __attribute__((address_space(1))) void*)(Bh + gb),
        (__attribute__((address_space(3))) void*)(sBh + linear*16), 16, 0, 0);
      __builtin_amdgcn_global_load_lds((const __attribute__((address_space(1))) void*)(Bl + gb),
        (__attribute__((address_space(3))) void*)(sBl + linear*16), 16, 0, 0);
    }
    __syncthreads();
    #pragma unroll
    for (int kk = 0; kk < 2; ++kk) {
      f16x8 ah[4], al[4], bh[4], bl[4];
      #pragma unroll
      for (int i=0;i<4;i++){
        int row = wy*64 + i*16 + r16;
        int sl = ((kk<<2) | g4) ^ (row & 7);
        ah[i] = *(const f16x8*)(sAh + row*128 + sl*16);
        al[i] = *(const f16x8*)(sAl + row*128 + sl*16);
      }
      #pragma unroll
      for (int j=0;j<4;j++){
        int row = wx*64 + j*16 + r16;
        int sl = ((kk<<2) | g4) ^ (row & 7);
        bh[j] = *(const f16x8*)(sBh + row*128 + sl*16);
        bl[j] = *(const f16x8*)(sBl + row*128 + sl*16);
      }
      #pragma unroll
      for (int i=0;i<4;i++)
        #pragma unroll
        for (int j=0;j<4;j++) {
          acc[i][j] = __builtin_amdgcn_mfma_f32_16x16x32_f16(ah[i], bh[j], acc[i][j], 0,0,0);
          acc[i][j] = __builtin_amdgcn_mfma_f32_16x16x32_f16(ah[i], bl[j], acc[i][j], 0,0,0);
          acc[i][j] = __builtin_amdgcn_mfma_f32_16x16x32_f16(al[i], bh[j], acc[i][j], 0,0,0);
        }
    }
    __syncthreads();
  }

  #pragma unroll
  for (int i=0;i<4;i++) {
    #pragma unroll
    for (int reg=0; reg<4; ++reg) {
      int m = m0 + wy*64 + i*16 + g4*4 + reg;
      #pragma unroll
      for (int j=0;j<4;j++) {
        int n = n0 + wx*64 + j*16 + r16;
        float v = acc[i][j][reg];
        if (EPI == 0) {
          C[(size_t)m*N + n] = v;
        } else {
          us hi, lo; splitf(v, hi, lo);
          Ch[(size_t)m*N + n] = hi;
          Cl[(size_t)m*N + n] = lo;
        }
      }
    }
  }
}

// ---------------------------------------------------------------------------
// bf16 GEMM (MoE path): C[M,N] = A[M,K]*B[N,K]^T.
// EPI: 1 = bf16 store, 2 = accout[m*N+n] += gate[m*8]*v
// ---------------------------------------------------------------------------
template<int EPI>
__global__ __launch_bounds__(256, 2) void gemm_bt(
    const us* __restrict__ A, const us* __restrict__ Bm,
    void* __restrict__ Cv, int M, int N, int K,
    const float* __restrict__ gate, float* __restrict__ accout)
{
  __shared__ char sm[32768];
  char* smA = sm;
  char* smB = sm + 16384;
  const int tid = threadIdx.x;
  const int m0 = blockIdx.y*128, n0 = blockIdx.x*128;
  const int wid = tid >> 6, lane = tid & 63;
  const int wy = wid >> 1, wx = wid & 1;
  const int r16 = lane & 15, g4 = lane >> 4;

  f32x4 acc[4][4];
  #pragma unroll
  for (int i=0;i<4;i++)
    #pragma unroll
    for(int j=0;j<4;j++) acc[i][j] = (f32x4)0.f;

  const int nkt = K >> 6;
  for (int kt = 0; kt < nkt; ++kt) {
    #pragma unroll
    for (int r = 0; r < 4; ++r) {
      int linear = r*256 + tid;
      int row = linear >> 3, ss = linear & 7;
      int sg = ss ^ (row & 7);
      __builtin_amdgcn_global_load_lds(
        (const __attribute__((address_space(1))) void*)(A + (size_t)(m0+row)*K + kt*64 + sg*8),
        (__attribute__((address_space(3))) void*)(smA + linear*16), 16, 0, 0);
      __builtin_amdgcn_global_load_lds(
        (const __attribute__((address_space(1))) void*)(Bm + (size_t)(n0+row)*K + kt*64 + sg*8),
        (__attribute__((address_space(3))) void*)(smB + linear*16), 16, 0, 0);
    }
    __syncthreads();
    #pragma unroll
    for (int kk = 0; kk < 2; ++kk) {
      bf16x8 af[4], bfr[4];
      #pragma unroll
      for (int i=0;i<4;i++){
        int row = wy*64 + i*16 + r16;
        int sl = ((kk<<2) | g4) ^ (row & 7);
        af[i] = *(const bf16x8*)(smA + row*128 + sl*16);
      }
      #pragma unroll
      for (int j=0;j<4;j++){
        int row = wx*64 + j*16 + r16;
        int sl = ((kk<<2) | g4) ^ (row & 7);
        bfr[j] = *(const bf16x8*)(smB + row*128 + sl*16);
      }
      #pragma unroll
      for (int i=0;i<4;i++)
        #pragma unroll
        for (int j=0;j<4;j++)
          acc[i][j] = __builtin_amdgcn_mfma_f32_16x16x32_bf16(af[i], bfr[j], acc[i][j], 0,0,0);
    }
    __syncthreads();
  }

  #pragma unroll
  for (int i=0;i<4;i++) {
    #pragma unroll
    for (int reg=0; reg<4; ++reg) {
      int m = m0 + wy*64 + i*16 + g4*4 + reg;
      float gm = (EPI == 2) ? gate[(size_t)m*8] : 0.f;
      #pragma unroll
      for (int j=0;j<4;j++) {
        int n = n0 + wx*64 + j*16 + r16;
        float v = acc[i][j][reg];
        if (EPI == 1) ((us*)Cv)[(size_t)m*N + n] = f2b(v);
        else          accout[(size_t)m*N + n] += gm * v;
      }
    }
  }
}

// ---------------------------------------------------------------------------
// RoPE cos/sin table. inv_freq computed via f64 pow -> correctly-rounded f32,
// matching numpy's f32 powf path bit-for-bit (modulo 2^-28 double-round risk).
// ---------------------------------------------------------------------------
__global__ void rope_table(const int* __restrict__ pos, float2* __restrict__ cs)
{
  int idx = blockIdx.x*256 + threadIdx.x;   // T*256
  int t = idx >> 8, j = idx & 255;
  float xj = (float)j * (1.0f/256.0f);               // exact
  float p32 = (float)pow(10000.0, (double)xj);       // ~correctly-rounded f32 powf
  float invf = 1.0f / p32;
  float ang = (float)pos[t] * invf;
  cs[idx] = make_float2(cosf(ang), sinf(ang));
}

// ---------------------------------------------------------------------------
// LN1 (two-pass var) -> xn1 fp16 hi/lo planes + roped K fp16 hi/lo planes
// ---------------------------------------------------------------------------
__global__ void ln1_kernel(const float* __restrict__ x, const float* __restrict__ g,
    const float* __restrict__ be, const float2* __restrict__ cs,
    us* __restrict__ xn1h, us* __restrict__ xn1l,
    us* __restrict__ Krh, us* __restrict__ Krl)
{
  const int row = blockIdx.x;           // b*T + t
  const int t = row & (T_-1);
  const int tid = threadIdx.x;
  __shared__ float red[8];
  float v0 = x[(size_t)row*D_ + tid];
  float v1 = x[(size_t)row*D_ + 256 + tid];
  const int wid = tid>>6, lane = tid&63;
  float s = v0 + v1;
  #pragma unroll
  for (int m=1; m<64; m<<=1) s += __shfl_xor(s,m);
  if (lane == 0) red[wid] = s;
  __syncthreads();
  s = red[0]+red[1]+red[2]+red[3];
  float mu = s * (1.f/D_);
  float d0 = v0-mu, d1 = v1-mu;
  float q = d0*d0 + d1*d1;
  #pragma unroll
  for (int m=1; m<64; m<<=1) q += __shfl_xor(q,m);
  __syncthreads();
  if (lane == 0) red[wid] = q;
  __syncthreads();
  q = red[0]+red[1]+red[2]+red[3];
  float var = q * (1.f/D_);
  float rs = rsqrtf(var + 1e-5f);
  float n0 = d0*rs*g[tid]     + be[tid];
  float n1 = d1*rs*g[tid+256] + be[tid+256];
  splitf(n0, xn1h[(size_t)row*D_ + tid],       xn1l[(size_t)row*D_ + tid]);
  splitf(n1, xn1h[(size_t)row*D_ + 256 + tid], xn1l[(size_t)row*D_ + 256 + tid]);
  float2 c = cs[(size_t)t*256 + tid];
  float k0 = n0*c.x - n1*c.y;
  float k1 = n1*c.x + n0*c.y;
  splitf(k0, Krh[(size_t)row*D_ + tid],       Krl[(size_t)row*D_ + tid]);
  splitf(k1, Krh[(size_t)row*D_ + 256 + tid], Krl[(size_t)row*D_ + 256 + tid]);
}

// ---------------------------------------------------------------------------
// Transpose-split: f32 (R,C) -> fp16 hi/lo planes (C,R)
// ---------------------------------------------------------------------------
__global__ void transpose_split(const float* __restrict__ in,
    us* __restrict__ outh, us* __restrict__ outl, int R, int C)
{
  __shared__ float tile[32][33];
  const int c0 = blockIdx.x*32, r0 = blockIdx.y*32;
  const int tc = threadIdx.x & 31, tr = threadIdx.x >> 5;  // tr in 0..7
  #pragma unroll
  for (int i=0;i<4;i++)
    tile[tr + 8*i][tc] = in[(size_t)(r0 + tr + 8*i)*C + c0 + tc];
  __syncthreads();
  #pragma unroll
  for (int i=0;i<4;i++) {
    float v = tile[tc][tr + 8*i];
    size_t o = (size_t)(c0 + tr + 8*i)*R + r0 + tc;
    splitf(v, outh[o], outl[o]);
  }
}

// cast f32 -> bf16, 4 elems/thread
__global__ void cast_bf16(const float* __restrict__ in, us* __restrict__ out, int n4)
{
  int i = blockIdx.x*256 + threadIdx.x;
  if (i >= n4) return;
  float4 v = ((const float4*)in)[i];
  union { us u[4]; uint2 v2; } r;
  r.u[0]=f2b(v.x); r.u[1]=f2b(v.y); r.u[2]=f2b(v.z); r.u[3]=f2b(v.w);
  ((uint2*)out)[i] = r.v2;
}

// cast w1/w3 (E,F,D) f32 into w13b (E, 2F, D) bf16 at row offset rowoff
__global__ void cast_w13(const float* __restrict__ in, us* __restrict__ out, int rowoff)
{
  int i = blockIdx.x*256 + threadIdx.x;   // E*F*D/4
  int e = i / (F_*D_/4);
  int rem = i - e*(F_*D_/4);
  float4 v = ((const float4*)in)[i];
  union { us u[4]; uint2 v2; } r;
  r.u[0]=f2b(v.x); r.u[1]=f2b(v.y); r.u[2]=f2b(v.z); r.u[3]=f2b(v.w);
  size_t ob = (size_t)e*(2*F_*D_/4) + (size_t)rowoff*(D_/4) + rem;
  ((uint2*)out)[ob] = r.v2;
}

// ---------------------------------------------------------------------------
// RoPE on f32 Q (B,T,H,D) then split to fp16 hi/lo planes
// ---------------------------------------------------------------------------
__global__ void rope_q_split(const float* __restrict__ Qf, const float2* __restrict__ cs,
    us* __restrict__ Qhp, us* __restrict__ Qlp)
{
  size_t idx = (size_t)blockIdx.x*256 + threadIdx.x;   // B*T*H*256
  int j = idx & 255;
  size_t rest = idx >> 8;
  int h = rest & 7;
  size_t bt = rest >> 3;
  int t = bt & (T_-1);
  size_t base = bt*HD + (size_t)h*D_ + j;
  float q1 = Qf[base], q2 = Qf[base+256];
  float2 c = cs[(size_t)t*256 + j];
  float r1 = q1*c.x - q2*c.y;
  float r2 = q2*c.x + q1*c.y;
  splitf(r1, Qhp[base],     Qlp[base]);
  splitf(r2, Qhp[base+256], Qlp[base+256]);
}

// ---------------------------------------------------------------------------
// Flash attention, fp16-split (3-product) QK and PV, f32 softmax (expf).
// Block = (b, h, q-tile of 64). 4 waves x 16 q-rows. Accumulate head outputs
// into Obsum (B,T,D) f32 via hardware fp32 atomics.
// ---------------------------------------------------------------------------
__global__ __launch_bounds__(256, 1) void attn_kernel(
    const us* __restrict__ Qhp, const us* __restrict__ Qlp,
    const us* __restrict__ Krh, const us* __restrict__ Krl,
    const us* __restrict__ Vth, const us* __restrict__ Vtl,
    float* __restrict__ Obsum)
{
  const int blk = blockIdx.x;
  const int qt = blk & 15, h = (blk >> 4) & 7, b = blk >> 7;
  const int wid = threadIdx.x >> 6, lane = threadIdx.x & 63;
  const int r16 = lane & 15, g4 = lane >> 4;
  const int qw = qt*64 + wid*16;
  __shared__ us pbh[4][16][80];   // 16B-aligned rows (80*2=160B)
  __shared__ us pbl[4][16][80];

  const us* qbase  = Qhp + (size_t)(b*T_ + qw + r16)*HD + (size_t)h*D_;
  const us* qlbase = Qlp + (size_t)(b*T_ + qw + r16)*HD + (size_t)h*D_;
  f16x8 qh[16];
  #pragma unroll
  for (int ks=0; ks<16; ++ks) qh[ks] = *(const f16x8*)(qbase + ks*32 + g4*8);

  f32x4 o[32];
  #pragma unroll
  for (int dg=0; dg<32; ++dg) o[dg] = (f32x4)0.f;
  float mrow[4] = {-1e30f,-1e30f,-1e30f,-1e30f};
  float lrow[4] = {0.f,0.f,0.f,0.f};
  const float scale = 0.044194173824159216f;  // 1/sqrt(512)

  const int ktmax = (qw + 15) >> 6;
  for (int kt = 0; kt <= ktmax; ++kt) {
    f32x4 s[4];
    #pragma unroll
    for (int jg=0;jg<4;jg++) s[jg] = (f32x4)0.f;
    const us* kbh = Krh + (size_t)(b*T_ + kt*64)*D_;
    const us* kbl = Krl + (size_t)(b*T_ + kt*64)*D_;
    #pragma unroll
    for (int ks=0; ks<16; ++ks) {
      f16x8 qlo = *(const f16x8*)(qlbase + ks*32 + g4*8);
      #pragma unroll
      for (int jg=0; jg<4; ++jg) {
        f16x8 kh = *(const f16x8*)(kbh + (size_t)(jg*16 + r16)*D_ + ks*32 + g4*8);
        f16x8 kl = *(const f16x8*)(kbl + (size_t)(jg*16 + r16)*D_ + ks*32 + g4*8);
        s[jg] = __builtin_amdgcn_mfma_f32_16x16x32_f16(qh[ks], kh, s[jg], 0,0,0);
        s[jg] = __builtin_amdgcn_mfma_f32_16x16x32_f16(qh[ks], kl, s[jg], 0,0,0);
        s[jg] = __builtin_amdgcn_mfma_f32_16x16x32_f16(qlo,    kh, s[jg], 0,0,0);
      }
    }
    float osc[4];
    #pragma unroll
    for (int reg=0; reg<4; ++reg) {
      const int row = qw + g4*4 + reg;
      float mx = -1e30f;
      #pragma unroll
      for (int jg=0;jg<4;jg++) {
        int col = kt*64 + jg*16 + r16;
        float v = s[jg][reg] * scale;
        v = (col <= row) ? v : -1e30f;
        s[jg][reg] = v;
        mx = fmaxf(mx, v);
      }
      mx = fmaxf(mx, __shfl_xor(mx, 1));
      mx = fmaxf(mx, __shfl_xor(mx, 2));
      mx = fmaxf(mx, __shfl_xor(mx, 4));
      mx = fmaxf(mx, __shfl_xor(mx, 8));
      float mnew = fmaxf(mrow[reg], mx);
      float sc = expf(mrow[reg] - mnew);
      float ps = 0.f;
      #pragma unroll
      for (int jg=0;jg<4;jg++) {
        float p = expf(s[jg][reg] - mnew);
        s[jg][reg] = p; ps += p;
      }
      ps += __shfl_xor(ps, 1); ps += __shfl_xor(ps, 2);
      ps += __shfl_xor(ps, 4); ps += __shfl_xor(ps, 8);
      lrow[reg] = lrow[reg]*sc + ps;
      mrow[reg] = mnew;
      osc[reg] = sc;
    }
    #pragma unroll
    for (int dg=0; dg<32; ++dg) {
      o[dg][0]*=osc[0]; o[dg][1]*=osc[1]; o[dg][2]*=osc[2]; o[dg][3]*=osc[3];
    }
    #pragma unroll
    for (int reg=0;reg<4;++reg)
      #pragma unroll
      for (int jg=0;jg<4;++jg)
        splitf(s[jg][reg], pbh[wid][g4*4+reg][jg*16+r16], pbl[wid][g4*4+reg][jg*16+r16]);
    const us* vbh = Vth + (size_t)h*D_*NTOK + (size_t)b*T_ + kt*64;
    const us* vbl = Vtl + (size_t)h*D_*NTOK + (size_t)b*T_ + kt*64;
    #pragma unroll
    for (int kg=0; kg<2; ++kg) {
      f16x8 pah = *(const f16x8*)(&pbh[wid][r16][kg*32 + g4*8]);
      f16x8 pal = *(const f16x8*)(&pbl[wid][r16][kg*32 + g4*8]);
      #pragma unroll
      for (int dg=0; dg<32; ++dg) {
        f16x8 vh = *(const f16x8*)(vbh + (size_t)(dg*16 + r16)*NTOK + kg*32 + g4*8);
        f16x8 vl = *(const f16x8*)(vbl + (size_t)(dg*16 + r16)*NTOK + kg*32 + g4*8);
        o[dg] = __builtin_amdgcn_mfma_f32_16x16x32_f16(pah, vh, o[dg], 0,0,0);
        o[dg] = __builtin_amdgcn_mfma_f32_16x16x32_f16(pah, vl, o[dg], 0,0,0);
        o[dg] = __builtin_amdgcn_mfma_f32_16x16x32_f16(pal, vh, o[dg], 0,0,0);
      }
    }
  }
  #pragma unroll
  for (int dg=0; dg<32; ++dg)
    #pragma unroll
    for (int reg=0; reg<4; ++reg) {
      size_t off = (size_t)(b*T_ + qw + g4*4 + reg)*D_ + dg*16 + r16;
      unsafeAtomicAdd(&Obsum[off], o[dg][reg] / lrow[reg]);
    }
}

// ---------------------------------------------------------------------------
// x1 = x + Obsum; out = x1 (f32); xn2f = LN2(x1) f32; xn2b = bf16(xn2f)
// ---------------------------------------------------------------------------
__global__ void resid_ln2_kernel(const float* __restrict__ x, const float* __restrict__ Obsum,
    const float* __restrict__ g, const float* __restrict__ be,
    float* __restrict__ out, float* __restrict__ xn2f, us* __restrict__ xn2b)
{
  const int row = blockIdx.x;
  const int tid = threadIdx.x;
  __shared__ float red[8];
  float a0 = x[(size_t)row*D_ + tid]       + Obsum[(size_t)row*D_ + tid];
  float a1 = x[(size_t)row*D_ + 256 + tid] + Obsum[(size_t)row*D_ + 256 + tid];
  out[(size_t)row*D_ + tid] = a0;
  out[(size_t)row*D_ + 256 + tid] = a1;
  const int wid = tid>>6, lane = tid&63;
  float s = a0 + a1;
  #pragma unroll
  for (int m=1; m<64; m<<=1) s += __shfl_xor(s,m);
  if (lane == 0) red[wid] = s;
  __syncthreads();
  s = red[0]+red[1]+red[2]+red[3];
  float mu = s * (1.f/D_);
  float d0 = a0-mu, d1 = a1-mu;
  float q = d0*d0 + d1*d1;
  #pragma unroll
  for (int m=1; m<64; m<<=1) q += __shfl_xor(q,m);
  __syncthreads();
  if (lane == 0) red[wid] = q;
  __syncthreads();
  q = red[0]+red[1]+red[2]+red[3];
  float var = q * (1.f/D_);
  float rs = rsqrtf(var + 1e-5f);
  float n0 = d0*rs*g[tid]     + be[tid];
  float n1 = d1*rs*g[tid+256] + be[tid+256];
  xn2f[(size_t)row*D_ + tid]       = n0;
  xn2f[(size_t)row*D_ + 256 + tid] = n1;
  xn2b[(size_t)row*D_ + tid]       = f2b(n0);
  xn2b[(size_t)row*D_ + 256 + tid] = f2b(n1);
}

// ---------------------------------------------------------------------------
// Router: one wave per token, f32 logits from f32 xn2
// ---------------------------------------------------------------------------
__global__ void router_kernel(const float* __restrict__ xn2f,
    const float* __restrict__ rw, float* __restrict__ gate_full)
{
  const int token = blockIdx.x*4 + (threadIdx.x>>6);
  const int lane = threadIdx.x & 63;
  float4 xa = *(const float4*)(xn2f + (size_t)token*D_ + lane*8);
  float4 xb = *(const float4*)(xn2f + (size_t)token*D_ + lane*8 + 4);
  float lg[8];
  #pragma unroll
  for (int e=0;e<E_;e++) {
    const float* w = rw + (size_t)e*D_ + lane*8;
    float4 wa = *(const float4*)w;
    float4 wb = *(const float4*)(w+4);
    float a = xa.x*wa.x + xa.y*wa.y + xa.z*wa.z + xa.w*wa.w
            + xb.x*wb.x + xb.y*wb.y + xb.z*wb.z + xb.w*wb.w;
    #pragma unroll
    for (int m=1;m<64;m<<=1) a += __shfl_xor(a,m);
    lg[e] = a;
  }
  if (lane == 0) {
    float mx = lg[0];
    #pragma unroll
    for (int e=1;e<E_;e++) mx = fmaxf(mx, lg[e]);
    float p[8];
    #pragma unroll
    for (int e=0;e<E_;e++) p[e] = expf(lg[e]-mx);
    int i1 = 0;
    #pragma unroll
    for (int e=1;e<E_;e++) if (p[e] > p[i1]) i1 = e;
    int i2 = (i1==0) ? 1 : 0;
    #pragma unroll
    for (int e=0;e<E_;e++) if (e != i1 && p[e] > p[i2]) i2 = e;
    float den = p[i1] + p[i2];
    #pragma unroll
    for (int e=0;e<E_;e++)
      gate_full[(size_t)token*8 + e] = (e==i1) ? p[i1]/den : ((e==i2) ? p[i2]/den : 0.f);
  }
}

// h = silu(H13b[:, :F]) * H13b[:, F:]  (bf16 in) -> bf16
__global__ void silu_mul(const us* __restrict__ H13b, us* __restrict__ hb)
{
  int i = blockIdx.x*256 + threadIdx.x;   // NTOK*F
  int n = i >> 10, f = i & (F_-1);
  float a = b2f(H13b[(size_t)n*2048 + f]);
  float c = b2f(H13b[(size_t)n*2048 + 1024 + f]);
  float s = a / (1.f + __expf(-a));
  hb[i] = f2b(s*c);
}

// ---------------------------------------------------------------------------
extern "C" void kernel_launch(void* const* d_in, const int* in_sizes, int n_in,
                              void* d_out, int out_size, void* d_ws, size_t ws_size,
                              hipStream_t stream)
{
  const float* x    = (const float*)d_in[0];
  const int*   pos  = (const int*)d_in[1];
  const float* ln1g = (const float*)d_in[2];
  const float* ln1b = (const float*)d_in[3];
  const float* M    = (const float*)d_in[4];
  const float* V    = (const float*)d_in[5];
  const float* ln2g = (const float*)d_in[6];
  const float* ln2b = (const float*)d_in[7];
  const float* rw   = (const float*)d_in[8];
  const float* w1   = (const float*)d_in[9];
  const float* w2   = (const float*)d_in[10];
  const float* w3   = (const float*)d_in[11];
  float* out = (float*)d_out;

  char* ws = (char*)d_ws;
  const size_t MB = (size_t)1 << 20;
  float2* cs   = (float2*)(ws + 0);          // 2MB
  us* xn1h = (us*)(ws + 2*MB);               // 4MB each below
  us* xn1l = (us*)(ws + 6*MB);
  us* Krh  = (us*)(ws + 10*MB);
  us* Krl  = (us*)(ws + 14*MB);
  us* Mth  = (us*)(ws + 18*MB);
  us* Mtl  = (us*)(ws + 22*MB);
  us* Vth  = (us*)(ws + 26*MB);
  us* Vtl  = (us*)(ws + 30*MB);
  float* xn2f = (float*)(ws + 34*MB);        // 8MB
  us* xn2b = (us*)(ws + 42*MB);              // 4MB
  float* gates = (float*)(ws + 46*MB);       // 128KB
  char* R = ws + 47*MB;                      // scratch region, 136MB peak
  float* Qf   = (float*)(R);                 // 64MB (dead after rope_q_split)
  us* valTh   = (us*)(R);                    // 32MB (aliases Qf after it dies)
  us* valTl   = (us*)(R + 32*MB);            // 32MB
  us* Qhp     = (us*)(R + 64*MB);            // 32MB
  us* Qlp     = (us*)(R + 96*MB);            // 32MB
  float* Obsum= (float*)(R + 128*MB);        // 8MB
  // MoE phase aliases (all attention buffers dead by then):
  us* w13b = (us*)(R);                       // 32MB
  us* w2b  = (us*)(R + 32*MB);               // 16MB
  us* H13b = (us*)(R + 48*MB);               // 16MB
  us* hb   = (us*)(R + 64*MB);               // 8MB

  rope_table<<<T_, 256, 0, stream>>>(pos, cs);
  ln1_kernel<<<NTOK, 256, 0, stream>>>(x, ln1g, ln1b, cs, xn1h, xn1l, Krh, Krl);
  transpose_split<<<dim3(HD/32, D_/32), 256, 0, stream>>>(M, Mth, Mtl, D_, HD);
  transpose_split<<<dim3(HD/32, D_/32), 256, 0, stream>>>(V, Vth, Vtl, D_, HD);

  // Q = xn1 @ M (f32), then rope+split
  gemm_split<0><<<dim3(HD/128, NTOK/128), 256, 0, stream>>>(
      xn1h, xn1l, Mth, Mtl, Qf, nullptr, nullptr, NTOK, HD, D_);
  rope_q_split<<<(B_*T_*H_*256)/256, 256, 0, stream>>>(Qf, cs, Qhp, Qlp);
  // valT[hd, token] = V^T @ xn1^T, split store (aliases Qf space)
  gemm_split<1><<<dim3(NTOK/128, HD/128), 256, 0, stream>>>(
      Vth, Vtl, xn1h, xn1l, nullptr, valTh, valTl, HD, NTOK, D_);

  hipMemsetAsync(Obsum, 0, (size_t)NTOK*D_*sizeof(float), stream);
  attn_kernel<<<B_*H_*(T_/64), 256, 0, stream>>>(Qhp, Qlp, Krh, Krl, valTh, valTl, Obsum);
  resid_ln2_kernel<<<NTOK, 256, 0, stream>>>(x, Obsum, ln2g, ln2b, out, xn2f, xn2b);
  router_kernel<<<NTOK/4, 256, 0, stream>>>(xn2f, rw, gates);

  // MoE (bf16): cast weights after attention phase (aliased region)
  cast_w13<<<(E_*F_*D_/4)/256, 256, 0, stream>>>(w1, w13b, 0);
  cast_w13<<<(E_*F_*D_/4)/256, 256, 0, stream>>>(w3, w13b, F_);
  cast_bf16<<<(E_*D_*F_/4)/256, 256, 0, stream>>>(w2, w2b, E_*D_*F_/4);

  for (int e = 0; e < E_; ++e) {
    gemm_bt<1><<<dim3(2*F_/128, NTOK/128), 256, 0, stream>>>(
        xn2b, w13b + (size_t)e*2*F_*D_, H13b, NTOK, 2*F_, D_, nullptr, nullptr);
    silu_mul<<<(NTOK*F_)/256, 256, 0, stream>>>(H13b, hb);
    gemm_bt<2><<<dim3(D_/128, NTOK/128), 256, 0, stream>>>(
        hb, w2b + (size_t)e*D_*F_, nullptr, NTOK, D_, F_, gates + e, out);
  }
}

// Round 4
// 832.243 us; speedup vs baseline: 2.1287x; 2.1287x over previous
//
#include <hip/hip_runtime.h>
#include <cstdint>
#include <cstddef>
#include <math.h>

#define B_ 4
#define T_ 1024
#define D_ 512
#define H_ 8
#define E_ 8
#define F_ 1024
#define NTOK (B_*T_)   // 4096
#define HD   (H_*D_)   // 4096

typedef float f32x4 __attribute__((ext_vector_type(4)));
typedef short bf16x8 __attribute__((ext_vector_type(8)));
typedef _Float16 f16x8 __attribute__((ext_vector_type(8)));
typedef unsigned short us;

union H16 { _Float16 h; unsigned short u; };

__device__ __forceinline__ us f2b(float f){
  union { float f; unsigned u; } v; v.f = f;
  unsigned r = v.u + 0x7fffu + ((v.u >> 16) & 1u);
  return (us)(r >> 16);
}
__device__ __forceinline__ float b2f(us h){
  union { unsigned u; float f; } v; v.u = ((unsigned)h) << 16; return v.f;
}
__device__ __forceinline__ void splitf(float x, us& hi, us& lo){
  H16 a, b;
  a.h = (_Float16)x;
  b.h = (_Float16)(x - (float)a.h);
  hi = a.u; lo = b.u;
}

// ---------------------------------------------------------------------------
// Generalized fp16-split GEMM: C[M,N] = A[M,K]*B[N,K]^T, A=Ah+Al, B=Bh+Bl.
// 3-product Markidis -> ~f32 accuracy. 128x128 tile, BK=64, 4 waves.
// Runtime lda/ldb/ldc + per-blockIdx.z strides zsA/zsB/zsC.
// MODE 0: f32 store. MODE 1: split hi/lo store.
// MODE 2: S-mode (skip upper-tri tiles), f32 store.
// MODE 3: PV-mode (K-loop limited to m0+128), atomic-add f32.
// ---------------------------------------------------------------------------
template<int MODE>
__global__ __launch_bounds__(256, 2) void gemm_ms(
    const us* __restrict__ Ah, const us* __restrict__ Al,
    const us* __restrict__ Bh, const us* __restrict__ Bl,
    float* __restrict__ C, us* __restrict__ Ch, us* __restrict__ Cl,
    int M, int N, int K, int lda, int ldb, int ldc,
    long zsA, long zsB, long zsC)
{
  if (MODE == 2 && blockIdx.x > blockIdx.y) return;
  const int z = blockIdx.z;
  Ah += (size_t)z*zsA; Al += (size_t)z*zsA;
  Bh += (size_t)z*zsB; Bl += (size_t)z*zsB;
  if (MODE == 1) { Ch += (size_t)z*zsC; Cl += (size_t)z*zsC; }
  else           { C  += (size_t)z*zsC; }

  __shared__ char sm[65536];
  char* sAh = sm;
  char* sAl = sm + 16384;
  char* sBh = sm + 32768;
  char* sBl = sm + 49152;
  const int tid = threadIdx.x;
  const int m0 = blockIdx.y*128, n0 = blockIdx.x*128;
  const int wid = tid >> 6, lane = tid & 63;
  const int wy = wid >> 1, wx = wid & 1;
  const int r16 = lane & 15, g4 = lane >> 4;

  f32x4 acc[4][4];
  #pragma unroll
  for (int i=0;i<4;i++)
    #pragma unroll
    for(int j=0;j<4;j++) acc[i][j] = (f32x4)0.f;

  int nkt = K >> 6;
  if (MODE == 3) { int kl = m0 + 128; if (kl < K) nkt = kl >> 6; }

  for (int kt = 0; kt < nkt; ++kt) {
    #pragma unroll
    for (int r = 0; r < 4; ++r) {
      int linear = r*256 + tid;
      int row = linear >> 3, ss = linear & 7;
      int sg = ss ^ (row & 7);
      size_t ga = (size_t)(m0+row)*lda + kt*64 + sg*8;
      size_t gb = (size_t)(n0+row)*ldb + kt*64 + sg*8;
      __builtin_amdgcn_global_load_lds((const __attribute__((address_space(1))) void*)(Ah + ga),
        (__attribute__((address_space(3))) void*)(sAh + linear*16), 16, 0, 0);
      __builtin_amdgcn_global_load_lds((const __attribute__((address_space(1))) void*)(Al + ga),
        (__attribute__((address_space(3))) void*)(sAl + linear*16), 16, 0, 0);
      __builtin_amdgcn_global_load_lds((const __attribute__((address_space(1))) void*)(Bh + gb),
        (__attribute__((address_space(3))) void*)(sBh + linear*16), 16, 0, 0);
      __builtin_amdgcn_global_load_lds((const __attribute__((address_space(1))) void*)(Bl + gb),
        (__attribute__((address_space(3))) void*)(sBl + linear*16), 16, 0, 0);
    }
    __syncthreads();
    #pragma unroll
    for (int kk = 0; kk < 2; ++kk) {
      f16x8 ah[4], al[4], bh[4], bl[4];
      #pragma unroll
      for (int i=0;i<4;i++){
        int row = wy*64 + i*16 + r16;
        int sl = ((kk<<2) | g4) ^ (row & 7);
        ah[i] = *(const f16x8*)(sAh + row*128 + sl*16);
        al[i] = *(const f16x8*)(sAl + row*128 + sl*16);
      }
      #pragma unroll
      for (int j=0;j<4;j++){
        int row = wx*64 + j*16 + r16;
        int sl = ((kk<<2) | g4) ^ (row & 7);
        bh[j] = *(const f16x8*)(sBh + row*128 + sl*16);
        bl[j] = *(const f16x8*)(sBl + row*128 + sl*16);
      }
      #pragma unroll
      for (int i=0;i<4;i++)
        #pragma unroll
        for (int j=0;j<4;j++) {
          acc[i][j] = __builtin_amdgcn_mfma_f32_16x16x32_f16(ah[i], bh[j], acc[i][j], 0,0,0);
          acc[i][j] = __builtin_amdgcn_mfma_f32_16x16x32_f16(ah[i], bl[j], acc[i][j], 0,0,0);
          acc[i][j] = __builtin_amdgcn_mfma_f32_16x16x32_f16(al[i], bh[j], acc[i][j], 0,0,0);
        }
    }
    __syncthreads();
  }

  #pragma unroll
  for (int i=0;i<4;i++) {
    #pragma unroll
    for (int reg=0; reg<4; ++reg) {
      int m = m0 + wy*64 + i*16 + g4*4 + reg;
      #pragma unroll
      for (int j=0;j<4;j++) {
        int n = n0 + wx*64 + j*16 + r16;
        float v = acc[i][j][reg];
        if (MODE == 0 || MODE == 2) {
          C[(size_t)m*ldc + n] = v;
        } else if (MODE == 1) {
          us hi, lo; splitf(v, hi, lo);
          Ch[(size_t)m*ldc + n] = hi;
          Cl[(size_t)m*ldc + n] = lo;
        } else {
          unsafeAtomicAdd(&C[(size_t)m*ldc + n], v);
        }
      }
    }
  }
}

// ---------------------------------------------------------------------------
// Row softmax on raw S (per-batch [H][T][T] f32). Applies scale + causal mask,
// normalizes, and overwrites each 4KB f32 row with fp16 hi plane (first 2KB)
// and fp16 lo plane (second 2KB): P = Phi + Plo, normalized.
// ---------------------------------------------------------------------------
__global__ void softmax_pk(float* __restrict__ S)
{
  const int row = blockIdx.x;          // h*T + t
  const int t = row & (T_-1);
  float* sr = S + (size_t)row*T_;
  const int tid = threadIdx.x;
  const int wid = tid >> 6, lane = tid & 63;
  __shared__ float red[8];
  const float scale = 0.044194173824159216f;  // 1/sqrt(512)
  float4 v = ((const float4*)sr)[tid];
  const int c0 = tid*4;
  float a[4];
  a[0] = (c0+0 <= t) ? v.x*scale : -1e30f;
  a[1] = (c0+1 <= t) ? v.y*scale : -1e30f;
  a[2] = (c0+2 <= t) ? v.z*scale : -1e30f;
  a[3] = (c0+3 <= t) ? v.w*scale : -1e30f;
  float mx = fmaxf(fmaxf(a[0],a[1]), fmaxf(a[2],a[3]));
  #pragma unroll
  for (int m=1; m<64; m<<=1) mx = fmaxf(mx, __shfl_xor(mx, m));
  if (lane == 0) red[wid] = mx;
  __syncthreads();
  mx = fmaxf(fmaxf(red[0],red[1]), fmaxf(red[2],red[3]));
  float p[4];
  float ps = 0.f;
  #pragma unroll
  for (int i=0;i<4;i++) { p[i] = expf(a[i] - mx); ps += p[i]; }
  #pragma unroll
  for (int m=1; m<64; m<<=1) ps += __shfl_xor(ps, m);
  __syncthreads();
  if (lane == 0) red[4+wid] = ps;
  __syncthreads();
  float l = red[4]+red[5]+red[6]+red[7];
  ushort4 hiv, lov;
  us h0,l0,h1,l1,h2,l2,h3,l3;
  splitf(p[0]/l, h0, l0); splitf(p[1]/l, h1, l1);
  splitf(p[2]/l, h2, l2); splitf(p[3]/l, h3, l3);
  hiv.x=h0; hiv.y=h1; hiv.z=h2; hiv.w=h3;
  lov.x=l0; lov.y=l1; lov.z=l2; lov.w=l3;
  us* oh = (us*)sr;
  *(ushort4*)(oh + c0)        = hiv;
  *(ushort4*)(oh + 1024 + c0) = lov;
}

// ---------------------------------------------------------------------------
// bf16 GEMM (MoE path): C[M,N] = A[M,K]*B[N,K]^T.
// EPI: 1 = bf16 store, 2 = accout[m*N+n] += gate[m*8]*v
// ---------------------------------------------------------------------------
template<int EPI>
__global__ __launch_bounds__(256, 2) void gemm_bt(
    const us* __restrict__ A, const us* __restrict__ Bm,
    void* __restrict__ Cv, int M, int N, int K,
    const float* __restrict__ gate, float* __restrict__ accout)
{
  __shared__ char sm[32768];
  char* smA = sm;
  char* smB = sm + 16384;
  const int tid = threadIdx.x;
  const int m0 = blockIdx.y*128, n0 = blockIdx.x*128;
  const int wid = tid >> 6, lane = tid & 63;
  const int wy = wid >> 1, wx = wid & 1;
  const int r16 = lane & 15, g4 = lane >> 4;

  f32x4 acc[4][4];
  #pragma unroll
  for (int i=0;i<4;i++)
    #pragma unroll
    for(int j=0;j<4;j++) acc[i][j] = (f32x4)0.f;

  const int nkt = K >> 6;
  for (int kt = 0; kt < nkt; ++kt) {
    #pragma unroll
    for (int r = 0; r < 4; ++r) {
      int linear = r*256 + tid;
      int row = linear >> 3, ss = linear & 7;
      int sg = ss ^ (row & 7);
      __builtin_amdgcn_global_load_lds(
        (const __attribute__((address_space(1))) void*)(A + (size_t)(m0+row)*K + kt*64 + sg*8),
        (__attribute__((address_space(3))) void*)(smA + linear*16), 16, 0, 0);
      __builtin_amdgcn_global_load_lds(
        (const __attribute__((address_space(1))) void*)(Bm + (size_t)(n0+row)*K + kt*64 + sg*8),
        (__attribute__((address_space(3))) void*)(smB + linear*16), 16, 0, 0);
    }
    __syncthreads();
    #pragma unroll
    for (int kk = 0; kk < 2; ++kk) {
      bf16x8 af[4], bfr[4];
      #pragma unroll
      for (int i=0;i<4;i++){
        int row = wy*64 + i*16 + r16;
        int sl = ((kk<<2) | g4) ^ (row & 7);
        af[i] = *(const bf16x8*)(smA + row*128 + sl*16);
      }
      #pragma unroll
      for (int j=0;j<4;j++){
        int row = wx*64 + j*16 + r16;
        int sl = ((kk<<2) | g4) ^ (row & 7);
        bfr[j] = *(const bf16x8*)(smB + row*128 + sl*16);
      }
      #pragma unroll
      for (int i=0;i<4;i++)
        #pragma unroll
        for (int j=0;j<4;j++)
          acc[i][j] = __builtin_amdgcn_mfma_f32_16x16x32_bf16(af[i], bfr[j], acc[i][j], 0,0,0);
    }
    __syncthreads();
  }

  #pragma unroll
  for (int i=0;i<4;i++) {
    #pragma unroll
    for (int reg=0; reg<4; ++reg) {
      int m = m0 + wy*64 + i*16 + g4*4 + reg;
      float gm = (EPI == 2) ? gate[(size_t)m*8] : 0.f;
      #pragma unroll
      for (int j=0;j<4;j++) {
        int n = n0 + wx*64 + j*16 + r16;
        float v = acc[i][j][reg];
        if (EPI == 1) ((us*)Cv)[(size_t)m*N + n] = f2b(v);
        else          accout[(size_t)m*N + n] += gm * v;
      }
    }
  }
}

// ---------------------------------------------------------------------------
// RoPE cos/sin table (f64 pow -> correctly-rounded f32 inv_freq)
// ---------------------------------------------------------------------------
__global__ void rope_table(const int* __restrict__ pos, float2* __restrict__ cs)
{
  int idx = blockIdx.x*256 + threadIdx.x;   // T*256
  int t = idx >> 8, j = idx & 255;
  float xj = (float)j * (1.0f/256.0f);
  float p32 = (float)pow(10000.0, (double)xj);
  float invf = 1.0f / p32;
  float ang = (float)pos[t] * invf;
  cs[idx] = make_float2(cosf(ang), sinf(ang));
}

// ---------------------------------------------------------------------------
// LN1 (two-pass var) -> xn1 fp16 hi/lo planes + roped K fp16 hi/lo planes
// ---------------------------------------------------------------------------
__global__ void ln1_kernel(const float* __restrict__ x, const float* __restrict__ g,
    const float* __restrict__ be, const float2* __restrict__ cs,
    us* __restrict__ xn1h, us* __restrict__ xn1l,
    us* __restrict__ Krh, us* __restrict__ Krl)
{
  const int row = blockIdx.x;           // b*T + t
  const int t = row & (T_-1);
  const int tid = threadIdx.x;
  __shared__ float red[8];
  float v0 = x[(size_t)row*D_ + tid];
  float v1 = x[(size_t)row*D_ + 256 + tid];
  const int wid = tid>>6, lane = tid&63;
  float s = v0 + v1;
  #pragma unroll
  for (int m=1; m<64; m<<=1) s += __shfl_xor(s,m);
  if (lane == 0) red[wid] = s;
  __syncthreads();
  s = red[0]+red[1]+red[2]+red[3];
  float mu = s * (1.f/D_);
  float d0 = v0-mu, d1 = v1-mu;
  float q = d0*d0 + d1*d1;
  #pragma unroll
  for (int m=1; m<64; m<<=1) q += __shfl_xor(q,m);
  __syncthreads();
  if (lane == 0) red[wid] = q;
  __syncthreads();
  q = red[0]+red[1]+red[2]+red[3];
  float var = q * (1.f/D_);
  float rs = rsqrtf(var + 1e-5f);
  float n0 = d0*rs*g[tid]     + be[tid];
  float n1 = d1*rs*g[tid+256] + be[tid+256];
  splitf(n0, xn1h[(size_t)row*D_ + tid],       xn1l[(size_t)row*D_ + tid]);
  splitf(n1, xn1h[(size_t)row*D_ + 256 + tid], xn1l[(size_t)row*D_ + 256 + tid]);
  float2 c = cs[(size_t)t*256 + tid];
  float k0 = n0*c.x - n1*c.y;
  float k1 = n1*c.x + n0*c.y;
  splitf(k0, Krh[(size_t)row*D_ + tid],       Krl[(size_t)row*D_ + tid]);
  splitf(k1, Krh[(size_t)row*D_ + 256 + tid], Krl[(size_t)row*D_ + 256 + tid]);
}

// ---------------------------------------------------------------------------
// Transpose-split: f32 (R,C) -> fp16 hi/lo planes (C,R)
// ---------------------------------------------------------------------------
__global__ void transpose_split(const float* __restrict__ in,
    us* __restrict__ outh, us* __restrict__ outl, int R, int C)
{
  __shared__ float tile[32][33];
  const int c0 = blockIdx.x*32, r0 = blockIdx.y*32;
  const int tc = threadIdx.x & 31, tr = threadIdx.x >> 5;  // tr in 0..7
  #pragma unroll
  for (int i=0;i<4;i++)
    tile[tr + 8*i][tc] = in[(size_t)(r0 + tr + 8*i)*C + c0 + tc];
  __syncthreads();
  #pragma unroll
  for (int i=0;i<4;i++) {
    float v = tile[tc][tr + 8*i];
    size_t o = (size_t)(c0 + tr + 8*i)*R + r0 + tc;
    splitf(v, outh[o], outl[o]);
  }
}

// cast f32 -> bf16, 4 elems/thread
__global__ void cast_bf16(const float* __restrict__ in, us* __restrict__ out, int n4)
{
  int i = blockIdx.x*256 + threadIdx.x;
  if (i >= n4) return;
  float4 v = ((const float4*)in)[i];
  union { us u[4]; uint2 v2; } r;
  r.u[0]=f2b(v.x); r.u[1]=f2b(v.y); r.u[2]=f2b(v.z); r.u[3]=f2b(v.w);
  ((uint2*)out)[i] = r.v2;
}

// cast w1/w3 (E,F,D) f32 into w13b (E, 2F, D) bf16 at row offset rowoff
__global__ void cast_w13(const float* __restrict__ in, us* __restrict__ out, int rowoff)
{
  int i = blockIdx.x*256 + threadIdx.x;   // E*F*D/4
  int e = i / (F_*D_/4);
  int rem = i - e*(F_*D_/4);
  float4 v = ((const float4*)in)[i];
  union { us u[4]; uint2 v2; } r;
  r.u[0]=f2b(v.x); r.u[1]=f2b(v.y); r.u[2]=f2b(v.z); r.u[3]=f2b(v.w);
  size_t ob = (size_t)e*(2*F_*D_/4) + (size_t)rowoff*(D_/4) + rem;
  ((uint2*)out)[ob] = r.v2;
}

// ---------------------------------------------------------------------------
// RoPE on f32 Q (B,T,H,D) then split to fp16 hi/lo planes
// ---------------------------------------------------------------------------
__global__ void rope_q_split(const float* __restrict__ Qf, const float2* __restrict__ cs,
    us* __restrict__ Qhp, us* __restrict__ Qlp)
{
  size_t idx = (size_t)blockIdx.x*256 + threadIdx.x;   // B*T*H*256
  int j = idx & 255;
  size_t rest = idx >> 8;
  int h = rest & 7;
  size_t bt = rest >> 3;
  int t = bt & (T_-1);
  size_t base = bt*HD + (size_t)h*D_ + j;
  float q1 = Qf[base], q2 = Qf[base+256];
  float2 c = cs[(size_t)t*256 + j];
  float r1 = q1*c.x - q2*c.y;
  float r2 = q2*c.x + q1*c.y;
  splitf(r1, Qhp[base],     Qlp[base]);
  splitf(r2, Qhp[base+256], Qlp[base+256]);
}

// ---------------------------------------------------------------------------
// x1 = x + Obsum; out = x1 (f32); xn2f = LN2(x1) f32; xn2b = bf16(xn2f)
// ---------------------------------------------------------------------------
__global__ void resid_ln2_kernel(const float* __restrict__ x, const float* __restrict__ Obsum,
    const float* __restrict__ g, const float* __restrict__ be,
    float* __restrict__ out, float* __restrict__ xn2f, us* __restrict__ xn2b)
{
  const int row = blockIdx.x;
  const int tid = threadIdx.x;
  __shared__ float red[8];
  float a0 = x[(size_t)row*D_ + tid]       + Obsum[(size_t)row*D_ + tid];
  float a1 = x[(size_t)row*D_ + 256 + tid] + Obsum[(size_t)row*D_ + 256 + tid];
  out[(size_t)row*D_ + tid] = a0;
  out[(size_t)row*D_ + 256 + tid] = a1;
  const int wid = tid>>6, lane = tid&63;
  float s = a0 + a1;
  #pragma unroll
  for (int m=1; m<64; m<<=1) s += __shfl_xor(s,m);
  if (lane == 0) red[wid] = s;
  __syncthreads();
  s = red[0]+red[1]+red[2]+red[3];
  float mu = s * (1.f/D_);
  float d0 = a0-mu, d1 = a1-mu;
  float q = d0*d0 + d1*d1;
  #pragma unroll
  for (int m=1; m<64; m<<=1) q += __shfl_xor(q,m);
  __syncthreads();
  if (lane == 0) red[wid] = q;
  __syncthreads();
  q = red[0]+red[1]+red[2]+red[3];
  float var = q * (1.f/D_);
  float rs = rsqrtf(var + 1e-5f);
  float n0 = d0*rs*g[tid]     + be[tid];
  float n1 = d1*rs*g[tid+256] + be[tid+256];
  xn2f[(size_t)row*D_ + tid]       = n0;
  xn2f[(size_t)row*D_ + 256 + tid] = n1;
  xn2b[(size_t)row*D_ + tid]       = f2b(n0);
  xn2b[(size_t)row*D_ + 256 + tid] = f2b(n1);
}

// ---------------------------------------------------------------------------
// Router: one wave per token, f32 logits from f32 xn2
// ---------------------------------------------------------------------------
__global__ void router_kernel(const float* __restrict__ xn2f,
    const float* __restrict__ rw, float* __restrict__ gate_full)
{
  const int token = blockIdx.x*4 + (threadIdx.x>>6);
  const int lane = threadIdx.x & 63;
  float4 xa = *(const float4*)(xn2f + (size_t)token*D_ + lane*8);
  float4 xb = *(const float4*)(xn2f + (size_t)token*D_ + lane*8 + 4);
  float lg[8];
  #pragma unroll
  for (int e=0;e<E_;e++) {
    const float* w = rw + (size_t)e*D_ + lane*8;
    float4 wa = *(const float4*)w;
    float4 wb = *(const float4*)(w+4);
    float a = xa.x*wa.x + xa.y*wa.y + xa.z*wa.z + xa.w*wa.w
            + xb.x*wb.x + xb.y*wb.y + xb.z*wb.z + xb.w*wb.w;
    #pragma unroll
    for (int m=1;m<64;m<<=1) a += __shfl_xor(a,m);
    lg[e] = a;
  }
  if (lane == 0) {
    float mx = lg[0];
    #pragma unroll
    for (int e=1;e<E_;e++) mx = fmaxf(mx, lg[e]);
    float p[8];
    #pragma unroll
    for (int e=0;e<E_;e++) p[e] = expf(lg[e]-mx);
    int i1 = 0;
    #pragma unroll
    for (int e=1;e<E_;e++) if (p[e] > p[i1]) i1 = e;
    int i2 = (i1==0) ? 1 : 0;
    #pragma unroll
    for (int e=0;e<E_;e++) if (e != i1 && p[e] > p[i2]) i2 = e;
    float den = p[i1] + p[i2];
    #pragma unroll
    for (int e=0;e<E_;e++)
      gate_full[(size_t)token*8 + e] = (e==i1) ? p[i1]/den : ((e==i2) ? p[i2]/den : 0.f);
  }
}

// h = silu(H13b[:, :F]) * H13b[:, F:]  (bf16 in) -> bf16
__global__ void silu_mul(const us* __restrict__ H13b, us* __restrict__ hb)
{
  int i = blockIdx.x*256 + threadIdx.x;   // NTOK*F
  int n = i >> 10, f = i & (F_-1);
  float a = b2f(H13b[(size_t)n*2048 + f]);
  float c = b2f(H13b[(size_t)n*2048 + 1024 + f]);
  float s = a / (1.f + __expf(-a));
  hb[i] = f2b(s*c);
}

// ---------------------------------------------------------------------------
extern "C" void kernel_launch(void* const* d_in, const int* in_sizes, int n_in,
                              void* d_out, int out_size, void* d_ws, size_t ws_size,
                              hipStream_t stream)
{
  const float* x    = (const float*)d_in[0];
  const int*   pos  = (const int*)d_in[1];
  const float* ln1g = (const float*)d_in[2];
  const float* ln1b = (const float*)d_in[3];
  const float* M    = (const float*)d_in[4];
  const float* V    = (const float*)d_in[5];
  const float* ln2g = (const float*)d_in[6];
  const float* ln2b = (const float*)d_in[7];
  const float* rw   = (const float*)d_in[8];
  const float* w1   = (const float*)d_in[9];
  const float* w2   = (const float*)d_in[10];
  const float* w3   = (const float*)d_in[11];
  float* out = (float*)d_out;

  char* ws = (char*)d_ws;
  const size_t MB = (size_t)1 << 20;
  // --- persistent across attention phase ---
  float2* cs   = (float2*)(ws + 0);           // 2MB
  us* Krh  = (us*)(ws + 2*MB);                // 4MB
  us* Krl  = (us*)(ws + 6*MB);                // 4MB
  // region 10..74MB: Qf (f32, 64MB) first, then valT planes after Qf dies
  float* Qf   = (float*)(ws + 10*MB);         // 64MB (dead after rope_q_split)
  us* valTh   = (us*)(ws + 10*MB);            // 32MB (written after Qf dead)
  us* valTl   = (us*)(ws + 42*MB);            // 32MB
  us* Qhp     = (us*)(ws + 74*MB);            // 32MB
  us* Qlp     = (us*)(ws + 106*MB);           // 32MB
  float* S    = (float*)(ws + 138*MB);        // 32MB per-batch scores (P in place)
  // projection-phase temporaries overlay the S region (dead before S written)
  us* xn1h = (us*)(ws + 138*MB);              // 4MB
  us* xn1l = (us*)(ws + 142*MB);              // 4MB
  us* Mth  = (us*)(ws + 146*MB);              // 8MB
  us* Mtl  = (us*)(ws + 154*MB);              // 8MB
  us* Vth  = (us*)(ws + 162*MB);              // 8MB
  us* Vtl  = (us*)(ws + 170*MB);              // 8MB (ends 178)
  float* Obsum = (float*)(ws + 180*MB);       // 8MB
  float* xn2f  = (float*)(ws + 188*MB);       // 8MB
  us* xn2b     = (us*)(ws + 196*MB);          // 4MB
  float* gates = (float*)(ws + 200*MB);       // 128KB
  // MoE temporaries overlay Qhp/Qlp/S (all dead after attention)
  us* w13b = (us*)(ws + 74*MB);               // 16MB (74..90)
  us* w2b  = (us*)(ws + 106*MB);              // 8MB  (106..114)
  us* H13b = (us*)(ws + 122*MB);              // 16MB (122..138)
  us* hb   = (us*)(ws + 138*MB);              // 8MB  (138..146, over dead S)
  // ^^ round-3 bug was hb at 130MB overlapping H13b's tail; now disjoint.

  rope_table<<<T_, 256, 0, stream>>>(pos, cs);
  ln1_kernel<<<NTOK, 256, 0, stream>>>(x, ln1g, ln1b, cs, xn1h, xn1l, Krh, Krl);
  transpose_split<<<dim3(HD/32, D_/32), 256, 0, stream>>>(M, Mth, Mtl, D_, HD);
  transpose_split<<<dim3(HD/32, D_/32), 256, 0, stream>>>(V, Vth, Vtl, D_, HD);

  // Q = xn1 @ M (f32) -> rope+split
  gemm_ms<0><<<dim3(HD/128, NTOK/128, 1), 256, 0, stream>>>(
      xn1h, xn1l, Mth, Mtl, Qf, nullptr, nullptr,
      NTOK, HD, D_, D_, D_, HD, 0, 0, 0);
  rope_q_split<<<(B_*T_*H_*256)/256, 256, 0, stream>>>(Qf, cs, Qhp, Qlp);
  // valT[h,d,b,t] = V^T @ xn1^T, split store (overlays dead Qf)
  gemm_ms<1><<<dim3(NTOK/128, HD/128, 1), 256, 0, stream>>>(
      Vth, Vtl, xn1h, xn1l, nullptr, valTh, valTl,
      HD, NTOK, D_, D_, D_, NTOK, 0, 0, 0);

  hipMemsetAsync(Obsum, 0, (size_t)NTOK*D_*sizeof(float), stream);

  // --- attention: per batch, S-GEMM (causal tiles) -> softmax -> PV ---
  for (int b = 0; b < B_; ++b) {
    // S[h,t,k] = Qr[b,t,h,:] . Kr[b,k,:]   (raw, unscaled)
    gemm_ms<2><<<dim3(T_/128, T_/128, H_), 256, 0, stream>>>(
        Qhp + (size_t)b*T_*HD, Qlp + (size_t)b*T_*HD,
        Krh + (size_t)b*T_*D_, Krl + (size_t)b*T_*D_,
        S, nullptr, nullptr,
        T_, T_, D_, HD, D_, T_,
        (long)D_, 0, (long)T_*T_);
    softmax_pk<<<H_*T_, 256, 0, stream>>>(S);
    // Obsum[b,t,d] += sum_h P[h,t,:] . valT[h,d,b,:]
    gemm_ms<3><<<dim3(D_/128, T_/128, H_), 256, 0, stream>>>(
        (const us*)S, (const us*)S + 1024,
        valTh + (size_t)b*T_, valTl + (size_t)b*T_,
        Obsum + (size_t)b*T_*D_, nullptr, nullptr,
        T_, D_, T_, 2048, NTOK, D_,
        (long)T_*2048, (long)D_*NTOK, 0);
  }

  resid_ln2_kernel<<<NTOK, 256, 0, stream>>>(x, Obsum, ln2g, ln2b, out, xn2f, xn2b);
  router_kernel<<<NTOK/4, 256, 0, stream>>>(xn2f, rw, gates);

  // MoE (bf16), weights cast into region freed by Qhp/Qlp
  cast_w13<<<(E_*F_*D_/4)/256, 256, 0, stream>>>(w1, w13b, 0);
  cast_w13<<<(E_*F_*D_/4)/256, 256, 0, stream>>>(w3, w13b, F_);
  cast_bf16<<<(E_*D_*F_/4)/256, 256, 0, stream>>>(w2, w2b, E_*D_*F_/4);

  for (int e = 0; e < E_; ++e) {
    gemm_bt<1><<<dim3(2*F_/128, NTOK/128), 256, 0, stream>>>(
        xn2b, w13b + (size_t)e*2*F_*D_, H13b, NTOK, 2*F_, D_, nullptr, nullptr);
    silu_mul<<<(NTOK*F_)/256, 256, 0, stream>>>(H13b, hb);
    gemm_bt<2><<<dim3(D_/128, NTOK/128), 256, 0, stream>>>(
        hb, w2b + (size_t)e*D_*F_, nullptr, NTOK, D_, F_, gates + e, out);
  }
}

// Round 5
// 617.439 us; speedup vs baseline: 2.8693x; 1.3479x over previous
//
#include <hip/hip_runtime.h>
#include <cstdint>
#include <cstddef>
#include <math.h>

#define B_ 4
#define T_ 1024
#define D_ 512
#define H_ 8
#define E_ 8
#define F_ 1024
#define NTOK (B_*T_)   // 4096
#define HD   (H_*D_)   // 4096

typedef float f32x4 __attribute__((ext_vector_type(4)));
typedef short bf16x8 __attribute__((ext_vector_type(8)));
typedef _Float16 f16x8 __attribute__((ext_vector_type(8)));
typedef unsigned short us;

union H16 { _Float16 h; unsigned short u; };

__device__ __forceinline__ us f2b(float f){
  union { float f; unsigned u; } v; v.f = f;
  unsigned r = v.u + 0x7fffu + ((v.u >> 16) & 1u);
  return (us)(r >> 16);
}
__device__ __forceinline__ float b2f(us h){
  union { unsigned u; float f; } v; v.u = ((unsigned)h) << 16; return v.f;
}
__device__ __forceinline__ void splitf(float x, us& hi, us& lo){
  H16 a, b;
  a.h = (_Float16)x;
  b.h = (_Float16)(x - (float)a.h);
  hi = a.u; lo = b.u;
}

// ---------------------------------------------------------------------------
// fp16-split GEMM: C[M,N] = A[M,K]*B[N,K]^T, A=Ah+Al, B=Bh+Bl (3-product
// Markidis, ~f32 accuracy). 128x128 tile, BK=64, 4 waves.
// MODE 1: split hi/lo store. MODE 2: S-mode (skip upper-tri tiles), f32 store.
// MODE 3: PV-mode (K limited to m0+128), atomic-add f32.
// MODE 4: RoPE epilogue (interleaved pair cols) + split store.
// ---------------------------------------------------------------------------
template<int MODE>
__global__ __launch_bounds__(256, 2) void gemm_ms(
    const us* __restrict__ Ah, const us* __restrict__ Al,
    const us* __restrict__ Bh, const us* __restrict__ Bl,
    float* __restrict__ C, us* __restrict__ Ch, us* __restrict__ Cl,
    int M, int N, int K, int lda, int ldb, int ldc,
    long zsA, long zsB, long zsC, const float2* __restrict__ cspar)
{
  if (MODE == 2 && blockIdx.x > blockIdx.y) return;
  const int z = blockIdx.z;
  Ah += (size_t)z*zsA; Al += (size_t)z*zsA;
  Bh += (size_t)z*zsB; Bl += (size_t)z*zsB;
  if (MODE == 1 || MODE == 4) { Ch += (size_t)z*zsC; Cl += (size_t)z*zsC; }
  else                        { C  += (size_t)z*zsC; }

  __shared__ char sm[65536];
  char* sAh = sm;
  char* sAl = sm + 16384;
  char* sBh = sm + 32768;
  char* sBl = sm + 49152;
  const int tid = threadIdx.x;
  const int m0 = blockIdx.y*128, n0 = blockIdx.x*128;
  const int wid = tid >> 6, lane = tid & 63;
  const int wy = wid >> 1, wx = wid & 1;
  const int r16 = lane & 15, g4 = lane >> 4;

  f32x4 acc[4][4];
  #pragma unroll
  for (int i=0;i<4;i++)
    #pragma unroll
    for(int j=0;j<4;j++) acc[i][j] = (f32x4)0.f;

  int nkt = K >> 6;
  if (MODE == 3) { int kl = m0 + 128; if (kl < K) nkt = kl >> 6; }

  for (int kt = 0; kt < nkt; ++kt) {
    #pragma unroll
    for (int r = 0; r < 4; ++r) {
      int linear = r*256 + tid;
      int row = linear >> 3, ss = linear & 7;
      int sg = ss ^ (row & 7);
      size_t ga = (size_t)(m0+row)*lda + kt*64 + sg*8;
      size_t gb = (size_t)(n0+row)*ldb + kt*64 + sg*8;
      __builtin_amdgcn_global_load_lds((const __attribute__((address_space(1))) void*)(Ah + ga),
        (__attribute__((address_space(3))) void*)(sAh + linear*16), 16, 0, 0);
      __builtin_amdgcn_global_load_lds((const __attribute__((address_space(1))) void*)(Al + ga),
        (__attribute__((address_space(3))) void*)(sAl + linear*16), 16, 0, 0);
      __builtin_amdgcn_global_load_lds((const __attribute__((address_space(1))) void*)(Bh + gb),
        (__attribute__((address_space(3))) void*)(sBh + linear*16), 16, 0, 0);
      __builtin_amdgcn_global_load_lds((const __attribute__((address_space(1))) void*)(Bl + gb),
        (__attribute__((address_space(3))) void*)(sBl + linear*16), 16, 0, 0);
    }
    __syncthreads();
    #pragma unroll
    for (int kk = 0; kk < 2; ++kk) {
      f16x8 ah[4], al[4], bh[4], bl[4];
      #pragma unroll
      for (int i=0;i<4;i++){
        int row = wy*64 + i*16 + r16;
        int sl = ((kk<<2) | g4) ^ (row & 7);
        ah[i] = *(const f16x8*)(sAh + row*128 + sl*16);
        al[i] = *(const f16x8*)(sAl + row*128 + sl*16);
      }
      #pragma unroll
      for (int j=0;j<4;j++){
        int row = wx*64 + j*16 + r16;
        int sl = ((kk<<2) | g4) ^ (row & 7);
        bh[j] = *(const f16x8*)(sBh + row*128 + sl*16);
        bl[j] = *(const f16x8*)(sBl + row*128 + sl*16);
      }
      #pragma unroll
      for (int i=0;i<4;i++)
        #pragma unroll
        for (int j=0;j<4;j++) {
          acc[i][j] = __builtin_amdgcn_mfma_f32_16x16x32_f16(ah[i], bh[j], acc[i][j], 0,0,0);
          acc[i][j] = __builtin_amdgcn_mfma_f32_16x16x32_f16(ah[i], bl[j], acc[i][j], 0,0,0);
          acc[i][j] = __builtin_amdgcn_mfma_f32_16x16x32_f16(al[i], bh[j], acc[i][j], 0,0,0);
        }
    }
    __syncthreads();
  }

  #pragma unroll
  for (int i=0;i<4;i++) {
    #pragma unroll
    for (int reg=0; reg<4; ++reg) {
      int m = m0 + wy*64 + i*16 + g4*4 + reg;
      int t = m & (T_-1);
      #pragma unroll
      for (int j=0;j<4;j++) {
        int n = n0 + wx*64 + j*16 + r16;
        float v = acc[i][j][reg];
        if (MODE == 2) {
          C[(size_t)m*ldc + n] = v;
        } else if (MODE == 1) {
          us hi, lo; splitf(v, hi, lo);
          Ch[(size_t)m*ldc + n] = hi;
          Cl[(size_t)m*ldc + n] = lo;
        } else if (MODE == 4) {
          float vp = __shfl_xor(v, 1);
          float2 c = cspar[(size_t)t*256 + ((n>>1) & 255)];
          float r = (r16 & 1) ? (v*c.x + vp*c.y) : (v*c.x - vp*c.y);
          us hi, lo; splitf(r, hi, lo);
          Ch[(size_t)m*ldc + n] = hi;
          Cl[(size_t)m*ldc + n] = lo;
        } else {
          unsafeAtomicAdd(&C[(size_t)m*ldc + n], v);
        }
      }
    }
  }
}

// ---------------------------------------------------------------------------
// Row softmax on raw S ([H][T][T] f32 per batch): scale + causal mask +
// normalize, overwrite row with fp16 hi plane (first 2KB) + lo plane.
// ---------------------------------------------------------------------------
__global__ void softmax_pk(float* __restrict__ S)
{
  const int row = blockIdx.x;          // h*T + t
  const int t = row & (T_-1);
  float* sr = S + (size_t)row*T_;
  const int tid = threadIdx.x;
  const int wid = tid >> 6, lane = tid & 63;
  __shared__ float red[8];
  const float scale = 0.044194173824159216f;  // 1/sqrt(512)
  float4 v = ((const float4*)sr)[tid];
  const int c0 = tid*4;
  float a[4];
  a[0] = (c0+0 <= t) ? v.x*scale : -1e30f;
  a[1] = (c0+1 <= t) ? v.y*scale : -1e30f;
  a[2] = (c0+2 <= t) ? v.z*scale : -1e30f;
  a[3] = (c0+3 <= t) ? v.w*scale : -1e30f;
  float mx = fmaxf(fmaxf(a[0],a[1]), fmaxf(a[2],a[3]));
  #pragma unroll
  for (int m=1; m<64; m<<=1) mx = fmaxf(mx, __shfl_xor(mx, m));
  if (lane == 0) red[wid] = mx;
  __syncthreads();
  mx = fmaxf(fmaxf(red[0],red[1]), fmaxf(red[2],red[3]));
  float p[4];
  float ps = 0.f;
  #pragma unroll
  for (int i=0;i<4;i++) { p[i] = expf(a[i] - mx); ps += p[i]; }
  #pragma unroll
  for (int m=1; m<64; m<<=1) ps += __shfl_xor(ps, m);
  __syncthreads();
  if (lane == 0) red[4+wid] = ps;
  __syncthreads();
  float l = red[4]+red[5]+red[6]+red[7];
  ushort4 hiv, lov;
  us h0,l0,h1,l1,h2,l2,h3,l3;
  splitf(p[0]/l, h0, l0); splitf(p[1]/l, h1, l1);
  splitf(p[2]/l, h2, l2); splitf(p[3]/l, h3, l3);
  hiv.x=h0; hiv.y=h1; hiv.z=h2; hiv.w=h3;
  lov.x=l0; lov.y=l1; lov.z=l2; lov.w=l3;
  us* oh = (us*)sr;
  *(ushort4*)(oh + c0)        = hiv;
  *(ushort4*)(oh + 1024 + c0) = lov;
}

// ---------------------------------------------------------------------------
// Sparse MoE w13 GEMM: per expert, gathered A rows (tok_idx), B = interleaved
// w1/w3 rows (col 2f = w1[f], 2f+1 = w3[f]). Fused SiLU epilogue via
// shfl_xor(1): h = silu(h1)*h3 -> hb[(e*4096+slot)*F + f] bf16.
// Grid (2F/128, 32, E); early-exit when m0 >= cnt[e].
// ---------------------------------------------------------------------------
__global__ __launch_bounds__(256, 2) void moe_w13(
    const us* __restrict__ xn2b, const us* __restrict__ w13b,
    const int* __restrict__ cnt, const int* __restrict__ tok_idx,
    us* __restrict__ hb)
{
  const int e = blockIdx.z;
  const int ce = cnt[e];
  const int m0 = blockIdx.y*128, n0 = blockIdx.x*128;
  if (m0 >= ce) return;
  __shared__ char sm[32768];
  __shared__ int sidx[128];
  char* smA = sm;
  char* smB = sm + 16384;
  const int tid = threadIdx.x;
  if (tid < 128) sidx[tid] = tok_idx[e*NTOK + m0 + tid] & (NTOK-1);
  __syncthreads();
  const int wid = tid >> 6, lane = tid & 63;
  const int wy = wid >> 1, wx = wid & 1;
  const int r16 = lane & 15, g4 = lane >> 4;
  const us* Bm = w13b + (size_t)e*2*F_*D_;

  f32x4 acc[4][4];
  #pragma unroll
  for (int i=0;i<4;i++)
    #pragma unroll
    for(int j=0;j<4;j++) acc[i][j] = (f32x4)0.f;

  for (int kt = 0; kt < 8; ++kt) {
    #pragma unroll
    for (int r = 0; r < 4; ++r) {
      int linear = r*256 + tid;
      int row = linear >> 3, ss = linear & 7;
      int sg = ss ^ (row & 7);
      int arow = sidx[row];
      __builtin_amdgcn_global_load_lds(
        (const __attribute__((address_space(1))) void*)(xn2b + (size_t)arow*D_ + kt*64 + sg*8),
        (__attribute__((address_space(3))) void*)(smA + linear*16), 16, 0, 0);
      __builtin_amdgcn_global_load_lds(
        (const __attribute__((address_space(1))) void*)(Bm + (size_t)(n0+row)*D_ + kt*64 + sg*8),
        (__attribute__((address_space(3))) void*)(smB + linear*16), 16, 0, 0);
    }
    __syncthreads();
    #pragma unroll
    for (int kk = 0; kk < 2; ++kk) {
      bf16x8 af[4], bfr[4];
      #pragma unroll
      for (int i=0;i<4;i++){
        int row = wy*64 + i*16 + r16;
        int sl = ((kk<<2) | g4) ^ (row & 7);
        af[i] = *(const bf16x8*)(smA + row*128 + sl*16);
      }
      #pragma unroll
      for (int j=0;j<4;j++){
        int row = wx*64 + j*16 + r16;
        int sl = ((kk<<2) | g4) ^ (row & 7);
        bfr[j] = *(const bf16x8*)(smB + row*128 + sl*16);
      }
      #pragma unroll
      for (int i=0;i<4;i++)
        #pragma unroll
        for (int j=0;j<4;j++)
          acc[i][j] = __builtin_amdgcn_mfma_f32_16x16x32_bf16(af[i], bfr[j], acc[i][j], 0,0,0);
    }
    __syncthreads();
  }

  #pragma unroll
  for (int i=0;i<4;i++) {
    #pragma unroll
    for (int reg=0; reg<4; ++reg) {
      int m = m0 + wy*64 + i*16 + g4*4 + reg;
      #pragma unroll
      for (int j=0;j<4;j++) {
        int n = n0 + wx*64 + j*16 + r16;
        float v = acc[i][j][reg];
        float vp = __shfl_xor(v, 1);
        if (!(r16 & 1)) {   // even lane: v = h1, vp = h3
          float hv = v / (1.f + __expf(-v)) * vp;
          hb[((size_t)e*NTOK + m)*F_ + (n>>1)] = f2b(hv);
        }
      }
    }
  }
}

// ---------------------------------------------------------------------------
// Sparse MoE w2 GEMM: A = hb (per-expert slots, K=F), B = w2b[e] (D rows).
// Epilogue scatter: out[tok*D + n] += gate * v (atomic across experts).
// Grid (D/128, 32, E); early-exit when m0 >= cnt[e].
// ---------------------------------------------------------------------------
__global__ __launch_bounds__(256, 2) void moe_w2(
    const us* __restrict__ hb, const us* __restrict__ w2b,
    const int* __restrict__ cnt, const int* __restrict__ tok_idx,
    const float* __restrict__ tok_gate, float* __restrict__ out)
{
  const int e = blockIdx.z;
  const int ce = cnt[e];
  const int m0 = blockIdx.y*128, n0 = blockIdx.x*128;
  if (m0 >= ce) return;
  __shared__ char sm[32768];
  char* smA = sm;
  char* smB = sm + 16384;
  const int tid = threadIdx.x;
  const int wid = tid >> 6, lane = tid & 63;
  const int wy = wid >> 1, wx = wid & 1;
  const int r16 = lane & 15, g4 = lane >> 4;
  const us* Am = hb  + (size_t)e*NTOK*F_;
  const us* Bm = w2b + (size_t)e*D_*F_;

  f32x4 acc[4][4];
  #pragma unroll
  for (int i=0;i<4;i++)
    #pragma unroll
    for(int j=0;j<4;j++) acc[i][j] = (f32x4)0.f;

  for (int kt = 0; kt < 16; ++kt) {
    #pragma unroll
    for (int r = 0; r < 4; ++r) {
      int linear = r*256 + tid;
      int row = linear >> 3, ss = linear & 7;
      int sg = ss ^ (row & 7);
      __builtin_amdgcn_global_load_lds(
        (const __attribute__((address_space(1))) void*)(Am + (size_t)(m0+row)*F_ + kt*64 + sg*8),
        (__attribute__((address_space(3))) void*)(smA + linear*16), 16, 0, 0);
      __builtin_amdgcn_global_load_lds(
        (const __attribute__((address_space(1))) void*)(Bm + (size_t)(n0+row)*F_ + kt*64 + sg*8),
        (__attribute__((address_space(3))) void*)(smB + linear*16), 16, 0, 0);
    }
    __syncthreads();
    #pragma unroll
    for (int kk = 0; kk < 2; ++kk) {
      bf16x8 af[4], bfr[4];
      #pragma unroll
      for (int i=0;i<4;i++){
        int row = wy*64 + i*16 + r16;
        int sl = ((kk<<2) | g4) ^ (row & 7);
        af[i] = *(const bf16x8*)(smA + row*128 + sl*16);
      }
      #pragma unroll
      for (int j=0;j<4;j++){
        int row = wx*64 + j*16 + r16;
        int sl = ((kk<<2) | g4) ^ (row & 7);
        bfr[j] = *(const bf16x8*)(smB + row*128 + sl*16);
      }
      #pragma unroll
      for (int i=0;i<4;i++)
        #pragma unroll
        for (int j=0;j<4;j++)
          acc[i][j] = __builtin_amdgcn_mfma_f32_16x16x32_bf16(af[i], bfr[j], acc[i][j], 0,0,0);
    }
    __syncthreads();
  }

  #pragma unroll
  for (int i=0;i<4;i++) {
    #pragma unroll
    for (int reg=0; reg<4; ++reg) {
      int m = m0 + wy*64 + i*16 + g4*4 + reg;
      if (m < ce) {
        int tok = tok_idx[e*NTOK + m] & (NTOK-1);
        float g = tok_gate[e*NTOK + m];
        #pragma unroll
        for (int j=0;j<4;j++) {
          int n = n0 + wx*64 + j*16 + r16;
          unsafeAtomicAdd(&out[(size_t)tok*D_ + n], g * acc[i][j][reg]);
        }
      }
    }
  }
}

// ---------------------------------------------------------------------------
// RoPE cos/sin table (f64 pow -> correctly-rounded f32 inv_freq)
// ---------------------------------------------------------------------------
__global__ void rope_table(const int* __restrict__ pos, float2* __restrict__ cs)
{
  int idx = blockIdx.x*256 + threadIdx.x;   // T*256
  int t = idx >> 8, j = idx & 255;
  float xj = (float)j * (1.0f/256.0f);
  float p32 = (float)pow(10000.0, (double)xj);
  float invf = 1.0f / p32;
  float ang = (float)pos[t] * invf;
  cs[idx] = make_float2(cosf(ang), sinf(ang));
}

// ---------------------------------------------------------------------------
// LN1 (two-pass var) -> xn1 fp16 hi/lo planes + roped K planes stored in
// INTERLEAVED pair order: col 2j = k[j], col 2j+1 = k[j+256].
// ---------------------------------------------------------------------------
__global__ void ln1_kernel(const float* __restrict__ x, const float* __restrict__ g,
    const float* __restrict__ be, const float2* __restrict__ cs,
    us* __restrict__ xn1h, us* __restrict__ xn1l,
    us* __restrict__ Krh, us* __restrict__ Krl)
{
  const int row = blockIdx.x;           // b*T + t
  const int t = row & (T_-1);
  const int tid = threadIdx.x;
  __shared__ float red[8];
  float v0 = x[(size_t)row*D_ + tid];
  float v1 = x[(size_t)row*D_ + 256 + tid];
  const int wid = tid>>6, lane = tid&63;
  float s = v0 + v1;
  #pragma unroll
  for (int m=1; m<64; m<<=1) s += __shfl_xor(s,m);
  if (lane == 0) red[wid] = s;
  __syncthreads();
  s = red[0]+red[1]+red[2]+red[3];
  float mu = s * (1.f/D_);
  float d0 = v0-mu, d1 = v1-mu;
  float q = d0*d0 + d1*d1;
  #pragma unroll
  for (int m=1; m<64; m<<=1) q += __shfl_xor(q,m);
  __syncthreads();
  if (lane == 0) red[wid] = q;
  __syncthreads();
  q = red[0]+red[1]+red[2]+red[3];
  float var = q * (1.f/D_);
  float rs = rsqrtf(var + 1e-5f);
  float n0 = d0*rs*g[tid]     + be[tid];
  float n1 = d1*rs*g[tid+256] + be[tid+256];
  splitf(n0, xn1h[(size_t)row*D_ + tid],       xn1l[(size_t)row*D_ + tid]);
  splitf(n1, xn1h[(size_t)row*D_ + 256 + tid], xn1l[(size_t)row*D_ + 256 + tid]);
  float2 c = cs[(size_t)t*256 + tid];
  float k0 = n0*c.x - n1*c.y;
  float k1 = n1*c.x + n0*c.y;
  us k0h,k0l,k1h,k1l;
  splitf(k0, k0h, k0l);
  splitf(k1, k1h, k1l);
  size_t kb = (size_t)row*D_ + 2*tid;
  *(unsigned*)(Krh + kb) = (unsigned)k0h | ((unsigned)k1h << 16);
  *(unsigned*)(Krl + kb) = (unsigned)k0l | ((unsigned)k1l << 16);
}

// ---------------------------------------------------------------------------
// Transpose-split: f32 (R,C) -> fp16 hi/lo planes (C,R). ROPE variant permutes
// dest rows within each 512-head so RoPE pairs are adjacent cols in Q-GEMM.
// ---------------------------------------------------------------------------
template<int ROPE>
__global__ void transpose_split(const float* __restrict__ in,
    us* __restrict__ outh, us* __restrict__ outl, int R, int C)
{
  __shared__ float tile[32][33];
  const int c0 = blockIdx.x*32, r0 = blockIdx.y*32;
  const int tc = threadIdx.x & 31, tr = threadIdx.x >> 5;  // tr in 0..7
  #pragma unroll
  for (int i=0;i<4;i++)
    tile[tr + 8*i][tc] = in[(size_t)(r0 + tr + 8*i)*C + c0 + tc];
  __syncthreads();
  #pragma unroll
  for (int i=0;i<4;i++) {
    float v = tile[tc][tr + 8*i];
    int j0 = c0 + tr + 8*i;
    int n = j0;
    if (ROPE) {
      int jh = j0 & 511;
      n = (j0 & ~511) | ((jh & 255) << 1) | (jh >> 8);
    }
    size_t o = (size_t)n*R + r0 + tc;
    splitf(v, outh[o], outl[o]);
  }
}

// cast f32 -> bf16, 4 elems/thread
__global__ void cast_bf16(const float* __restrict__ in, us* __restrict__ out, int n4)
{
  int i = blockIdx.x*256 + threadIdx.x;
  if (i >= n4) return;
  float4 v = ((const float4*)in)[i];
  union { us u[4]; uint2 v2; } r;
  r.u[0]=f2b(v.x); r.u[1]=f2b(v.y); r.u[2]=f2b(v.z); r.u[3]=f2b(v.w);
  ((uint2*)out)[i] = r.v2;
}

// cast w1/w3 (E,F,D) f32 into w13b (E, 2F, D) bf16 with row INTERLEAVE:
// dest row 2f+par (par=0 for w1, 1 for w3)
__global__ void cast_w13(const float* __restrict__ in, us* __restrict__ out, int par)
{
  int i = blockIdx.x*256 + threadIdx.x;   // E*F*D/4
  int e = i / (F_*D_/4);
  int rem = i - e*(F_*D_/4);
  int f = rem / (D_/4);
  int d4 = rem - f*(D_/4);
  float4 v = ((const float4*)in)[i];
  union { us u[4]; uint2 v2; } r;
  r.u[0]=f2b(v.x); r.u[1]=f2b(v.y); r.u[2]=f2b(v.z); r.u[3]=f2b(v.w);
  size_t ob = (size_t)e*(2*F_*D_/4) + (size_t)(2*f+par)*(D_/4) + d4;
  ((uint2*)out)[ob] = r.v2;
}

// ---------------------------------------------------------------------------
// x1 = x + Obsum; out = x1 (f32); xn2f = LN2(x1) f32; xn2b = bf16(xn2f)
// ---------------------------------------------------------------------------
__global__ void resid_ln2_kernel(const float* __restrict__ x, const float* __restrict__ Obsum,
    const float* __restrict__ g, const float* __restrict__ be,
    float* __restrict__ out, float* __restrict__ xn2f, us* __restrict__ xn2b)
{
  const int row = blockIdx.x;
  const int tid = threadIdx.x;
  __shared__ float red[8];
  float a0 = x[(size_t)row*D_ + tid]       + Obsum[(size_t)row*D_ + tid];
  float a1 = x[(size_t)row*D_ + 256 + tid] + Obsum[(size_t)row*D_ + 256 + tid];
  out[(size_t)row*D_ + tid] = a0;
  out[(size_t)row*D_ + 256 + tid] = a1;
  const int wid = tid>>6, lane = tid&63;
  float s = a0 + a1;
  #pragma unroll
  for (int m=1; m<64; m<<=1) s += __shfl_xor(s,m);
  if (lane == 0) red[wid] = s;
  __syncthreads();
  s = red[0]+red[1]+red[2]+red[3];
  float mu = s * (1.f/D_);
  float d0 = a0-mu, d1 = a1-mu;
  float q = d0*d0 + d1*d1;
  #pragma unroll
  for (int m=1; m<64; m<<=1) q += __shfl_xor(q,m);
  __syncthreads();
  if (lane == 0) red[wid] = q;
  __syncthreads();
  q = red[0]+red[1]+red[2]+red[3];
  float var = q * (1.f/D_);
  float rs = rsqrtf(var + 1e-5f);
  float n0 = d0*rs*g[tid]     + be[tid];
  float n1 = d1*rs*g[tid+256] + be[tid+256];
  xn2f[(size_t)row*D_ + tid]       = n0;
  xn2f[(size_t)row*D_ + 256 + tid] = n1;
  xn2b[(size_t)row*D_ + tid]       = f2b(n0);
  xn2b[(size_t)row*D_ + 256 + tid] = f2b(n1);
}

// ---------------------------------------------------------------------------
// Router: one wave per token; top-2 -> per-expert slot lists via atomics.
// ---------------------------------------------------------------------------
__global__ void router_kernel(const float* __restrict__ xn2f,
    const float* __restrict__ rw, int* __restrict__ cnt,
    int* __restrict__ tok_idx, float* __restrict__ tok_gate)
{
  const int token = blockIdx.x*4 + (threadIdx.x>>6);
  const int lane = threadIdx.x & 63;
  float4 xa = *(const float4*)(xn2f + (size_t)token*D_ + lane*8);
  float4 xb = *(const float4*)(xn2f + (size_t)token*D_ + lane*8 + 4);
  float lg[8];
  #pragma unroll
  for (int e=0;e<E_;e++) {
    const float* w = rw + (size_t)e*D_ + lane*8;
    float4 wa = *(const float4*)w;
    float4 wb = *(const float4*)(w+4);
    float a = xa.x*wa.x + xa.y*wa.y + xa.z*wa.z + xa.w*wa.w
            + xb.x*wb.x + xb.y*wb.y + xb.z*wb.z + xb.w*wb.w;
    #pragma unroll
    for (int m=1;m<64;m<<=1) a += __shfl_xor(a,m);
    lg[e] = a;
  }
  if (lane == 0) {
    float mx = lg[0];
    #pragma unroll
    for (int e=1;e<E_;e++) mx = fmaxf(mx, lg[e]);
    float p[8];
    #pragma unroll
    for (int e=0;e<E_;e++) p[e] = expf(lg[e]-mx);
    int i1 = 0;
    #pragma unroll
    for (int e=1;e<E_;e++) if (p[e] > p[i1]) i1 = e;
    int i2 = (i1==0) ? 1 : 0;
    #pragma unroll
    for (int e=0;e<E_;e++) if (e != i1 && p[e] > p[i2]) i2 = e;
    float den = p[i1] + p[i2];
    int s1 = atomicAdd(&cnt[i1], 1);
    tok_idx[i1*NTOK + s1]  = token;
    tok_gate[i1*NTOK + s1] = p[i1]/den;
    int s2 = atomicAdd(&cnt[i2], 1);
    tok_idx[i2*NTOK + s2]  = token;
    tok_gate[i2*NTOK + s2] = p[i2]/den;
  }
}

// ---------------------------------------------------------------------------
extern "C" void kernel_launch(void* const* d_in, const int* in_sizes, int n_in,
                              void* d_out, int out_size, void* d_ws, size_t ws_size,
                              hipStream_t stream)
{
  const float* x    = (const float*)d_in[0];
  const int*   pos  = (const int*)d_in[1];
  const float* ln1g = (const float*)d_in[2];
  const float* ln1b = (const float*)d_in[3];
  const float* M    = (const float*)d_in[4];
  const float* V    = (const float*)d_in[5];
  const float* ln2g = (const float*)d_in[6];
  const float* ln2b = (const float*)d_in[7];
  const float* rw   = (const float*)d_in[8];
  const float* w1   = (const float*)d_in[9];
  const float* w2   = (const float*)d_in[10];
  const float* w3   = (const float*)d_in[11];
  float* out = (float*)d_out;

  char* ws = (char*)d_ws;
  const size_t MB = (size_t)1 << 20;
  // --- persistent across attention phase ---
  float2* cs  = (float2*)(ws + 0);            // 2MB
  us* Krh  = (us*)(ws + 2*MB);                // 4MB  (interleaved pair order)
  us* Krl  = (us*)(ws + 6*MB);                // 4MB
  us* valTh   = (us*)(ws + 10*MB);            // 32MB (10..42)
  us* valTl   = (us*)(ws + 42*MB);            // 32MB (42..74)
  us* Qhp     = (us*)(ws + 74*MB);            // 32MB (74..106, roped+interleaved)
  us* Qlp     = (us*)(ws + 106*MB);           // 32MB (106..138)
  float* S    = (float*)(ws + 138*MB);        // 32MB per-batch scores (P in place)
  // projection-phase temporaries overlay the S region (dead before S written)
  us* xn1h = (us*)(ws + 138*MB);              // 4MB
  us* xn1l = (us*)(ws + 142*MB);              // 4MB
  us* Mth  = (us*)(ws + 146*MB);              // 8MB
  us* Mtl  = (us*)(ws + 154*MB);              // 8MB
  us* Vth  = (us*)(ws + 162*MB);              // 8MB
  us* Vtl  = (us*)(ws + 170*MB);              // 8MB (ends 178)
  float* Obsum = (float*)(ws + 180*MB);       // 8MB
  float* xn2f  = (float*)(ws + 188*MB);       // 8MB
  us* xn2b     = (us*)(ws + 196*MB);          // 4MB
  int*   cnt      = (int*)  (ws + 200*MB);              // 32B
  int*   tok_idx  = (int*)  (ws + 200*MB + 4096);       // 128KB
  float* tok_gate = (float*)(ws + 200*MB + 4096 + 128*1024); // 128KB
  // MoE temporaries overlay attention-dead regions
  us* w13b = (us*)(ws + 10*MB);               // 16MB (over valTh, dead post-attn)
  us* w2b  = (us*)(ws + 26*MB);               // 8MB  (26..34)
  us* hb   = (us*)(ws + 74*MB);               // 64MB (over Qhp/Qlp, 74..138)

  rope_table<<<T_, 256, 0, stream>>>(pos, cs);
  ln1_kernel<<<NTOK, 256, 0, stream>>>(x, ln1g, ln1b, cs, xn1h, xn1l, Krh, Krl);
  transpose_split<1><<<dim3(HD/32, D_/32), 256, 0, stream>>>(M, Mth, Mtl, D_, HD);
  transpose_split<0><<<dim3(HD/32, D_/32), 256, 0, stream>>>(V, Vth, Vtl, D_, HD);

  // Q = rope(xn1 @ M) fused epilogue -> Qhp/Qlp (interleaved pair order)
  gemm_ms<4><<<dim3(HD/128, NTOK/128, 1), 256, 0, stream>>>(
      xn1h, xn1l, Mth, Mtl, nullptr, Qhp, Qlp,
      NTOK, HD, D_, D_, D_, HD, 0, 0, 0, cs);
  // valT[h,d,b,t] = V^T @ xn1^T, split store
  gemm_ms<1><<<dim3(NTOK/128, HD/128, 1), 256, 0, stream>>>(
      Vth, Vtl, xn1h, xn1l, nullptr, valTh, valTl,
      HD, NTOK, D_, D_, D_, NTOK, 0, 0, 0, nullptr);

  hipMemsetAsync(Obsum, 0, (size_t)NTOK*D_*sizeof(float), stream);

  // --- attention: per batch, S-GEMM (causal tiles) -> softmax -> PV ---
  for (int b = 0; b < B_; ++b) {
    gemm_ms<2><<<dim3(T_/128, T_/128, H_), 256, 0, stream>>>(
        Qhp + (size_t)b*T_*HD, Qlp + (size_t)b*T_*HD,
        Krh + (size_t)b*T_*D_, Krl + (size_t)b*T_*D_,
        S, nullptr, nullptr,
        T_, T_, D_, HD, D_, T_,
        (long)D_, 0, (long)T_*T_, nullptr);
    softmax_pk<<<H_*T_, 256, 0, stream>>>(S);
    gemm_ms<3><<<dim3(D_/128, T_/128, H_), 256, 0, stream>>>(
        (const us*)S, (const us*)S + 1024,
        valTh + (size_t)b*T_, valTl + (size_t)b*T_,
        Obsum + (size_t)b*T_*D_, nullptr, nullptr,
        T_, D_, T_, 2048, NTOK, D_,
        (long)T_*2048, (long)D_*NTOK, 0, nullptr);
  }

  resid_ln2_kernel<<<NTOK, 256, 0, stream>>>(x, Obsum, ln2g, ln2b, out, xn2f, xn2b);
  hipMemsetAsync(cnt, 0, E_*sizeof(int), stream);
  router_kernel<<<NTOK/4, 256, 0, stream>>>(xn2f, rw, cnt, tok_idx, tok_gate);

  // MoE weights (regions freed after attention)
  cast_w13<<<(E_*F_*D_/4)/256, 256, 0, stream>>>(w1, w13b, 0);
  cast_w13<<<(E_*F_*D_/4)/256, 256, 0, stream>>>(w3, w13b, 1);
  cast_bf16<<<(E_*D_*F_/4)/256, 256, 0, stream>>>(w2, w2b, E_*D_*F_/4);

  // Sparse MoE: gathered w13 GEMM (fused silu) then w2 GEMM (scatter-add)
  moe_w13<<<dim3(2*F_/128, NTOK/128, E_), 256, 0, stream>>>(
      xn2b, w13b, cnt, tok_idx, hb);
  moe_w2<<<dim3(D_/128, NTOK/128, E_), 256, 0, stream>>>(
      hb, w2b, cnt, tok_idx, tok_gate, out);
}

// Round 6
// 535.891 us; speedup vs baseline: 3.3059x; 1.1522x over previous
//
#include <hip/hip_runtime.h>
#include <cstdint>
#include <cstddef>
#include <math.h>

#define B_ 4
#define T_ 1024
#define D_ 512
#define H_ 8
#define E_ 8
#define F_ 1024
#define NTOK (B_*T_)   // 4096
#define HD   (H_*D_)   // 4096

typedef float f32x4 __attribute__((ext_vector_type(4)));
typedef short bf16x8 __attribute__((ext_vector_type(8)));
typedef _Float16 f16x8 __attribute__((ext_vector_type(8)));
typedef unsigned short us;

union H16 { _Float16 h; unsigned short u; };

__device__ __forceinline__ us f2b(float f){
  union { float f; unsigned u; } v; v.f = f;
  unsigned r = v.u + 0x7fffu + ((v.u >> 16) & 1u);
  return (us)(r >> 16);
}
__device__ __forceinline__ float b2f(us h){
  union { unsigned u; float f; } v; v.u = ((unsigned)h) << 16; return v.f;
}
__device__ __forceinline__ void splitf(float x, us& hi, us& lo){
  H16 a, b;
  a.h = (_Float16)x;
  b.h = (_Float16)(x - (float)a.h);
  hi = a.u; lo = b.u;
}

// ---------------------------------------------------------------------------
// fp16-split GEMM: C[M,N] = A[M,K]*B[N,K]^T, A=Ah+Al, B=Bh+Bl (3-product
// Markidis, ~f32 accuracy). 128x128 tile, BK=64, 4 waves.
// MODE 1: split hi/lo store. MODE 2: S-mode (skip upper-tri tiles), f32 store.
// MODE 3: PV-mode (K limited to m0+128), atomic-add f32.
// MODE 4: RoPE epilogue (interleaved pair cols) + split store.
// ---------------------------------------------------------------------------
template<int MODE>
__global__ __launch_bounds__(256, 2) void gemm_ms(
    const us* __restrict__ Ah, const us* __restrict__ Al,
    const us* __restrict__ Bh, const us* __restrict__ Bl,
    float* __restrict__ C, us* __restrict__ Ch, us* __restrict__ Cl,
    int M, int N, int K, int lda, int ldb, int ldc,
    long zsA, long zsB, long zsC, const float2* __restrict__ cspar)
{
  if (MODE == 2 && blockIdx.x > blockIdx.y) return;
  const int z = blockIdx.z;
  Ah += (size_t)z*zsA; Al += (size_t)z*zsA;
  Bh += (size_t)z*zsB; Bl += (size_t)z*zsB;
  if (MODE == 1 || MODE == 4) { Ch += (size_t)z*zsC; Cl += (size_t)z*zsC; }
  else                        { C  += (size_t)z*zsC; }

  __shared__ char sm[65536];
  char* sAh = sm;
  char* sAl = sm + 16384;
  char* sBh = sm + 32768;
  char* sBl = sm + 49152;
  const int tid = threadIdx.x;
  const int m0 = blockIdx.y*128, n0 = blockIdx.x*128;
  const int wid = tid >> 6, lane = tid & 63;
  const int wy = wid >> 1, wx = wid & 1;
  const int r16 = lane & 15, g4 = lane >> 4;

  f32x4 acc[4][4];
  #pragma unroll
  for (int i=0;i<4;i++)
    #pragma unroll
    for(int j=0;j<4;j++) acc[i][j] = (f32x4)0.f;

  int nkt = K >> 6;
  if (MODE == 3) { int kl = m0 + 128; if (kl < K) nkt = kl >> 6; }

  for (int kt = 0; kt < nkt; ++kt) {
    #pragma unroll
    for (int r = 0; r < 4; ++r) {
      int linear = r*256 + tid;
      int row = linear >> 3, ss = linear & 7;
      int sg = ss ^ (row & 7);
      size_t ga = (size_t)(m0+row)*lda + kt*64 + sg*8;
      size_t gb = (size_t)(n0+row)*ldb + kt*64 + sg*8;
      __builtin_amdgcn_global_load_lds((const __attribute__((address_space(1))) void*)(Ah + ga),
        (__attribute__((address_space(3))) void*)(sAh + linear*16), 16, 0, 0);
      __builtin_amdgcn_global_load_lds((const __attribute__((address_space(1))) void*)(Al + ga),
        (__attribute__((address_space(3))) void*)(sAl + linear*16), 16, 0, 0);
      __builtin_amdgcn_global_load_lds((const __attribute__((address_space(1))) void*)(Bh + gb),
        (__attribute__((address_space(3))) void*)(sBh + linear*16), 16, 0, 0);
      __builtin_amdgcn_global_load_lds((const __attribute__((address_space(1))) void*)(Bl + gb),
        (__attribute__((address_space(3))) void*)(sBl + linear*16), 16, 0, 0);
    }
    __syncthreads();
    #pragma unroll
    for (int kk = 0; kk < 2; ++kk) {
      f16x8 ah[4], al[4], bh[4], bl[4];
      #pragma unroll
      for (int i=0;i<4;i++){
        int row = wy*64 + i*16 + r16;
        int sl = ((kk<<2) | g4) ^ (row & 7);
        ah[i] = *(const f16x8*)(sAh + row*128 + sl*16);
        al[i] = *(const f16x8*)(sAl + row*128 + sl*16);
      }
      #pragma unroll
      for (int j=0;j<4;j++){
        int row = wx*64 + j*16 + r16;
        int sl = ((kk<<2) | g4) ^ (row & 7);
        bh[j] = *(const f16x8*)(sBh + row*128 + sl*16);
        bl[j] = *(const f16x8*)(sBl + row*128 + sl*16);
      }
      #pragma unroll
      for (int i=0;i<4;i++)
        #pragma unroll
        for (int j=0;j<4;j++) {
          acc[i][j] = __builtin_amdgcn_mfma_f32_16x16x32_f16(ah[i], bh[j], acc[i][j], 0,0,0);
          acc[i][j] = __builtin_amdgcn_mfma_f32_16x16x32_f16(ah[i], bl[j], acc[i][j], 0,0,0);
          acc[i][j] = __builtin_amdgcn_mfma_f32_16x16x32_f16(al[i], bh[j], acc[i][j], 0,0,0);
        }
    }
    __syncthreads();
  }

  #pragma unroll
  for (int i=0;i<4;i++) {
    #pragma unroll
    for (int reg=0; reg<4; ++reg) {
      int m = m0 + wy*64 + i*16 + g4*4 + reg;
      int t = m & (T_-1);
      #pragma unroll
      for (int j=0;j<4;j++) {
        int n = n0 + wx*64 + j*16 + r16;
        float v = acc[i][j][reg];
        if (MODE == 2) {
          C[(size_t)m*ldc + n] = v;
        } else if (MODE == 1) {
          us hi, lo; splitf(v, hi, lo);
          Ch[(size_t)m*ldc + n] = hi;
          Cl[(size_t)m*ldc + n] = lo;
        } else if (MODE == 4) {
          float vp = __shfl_xor(v, 1);
          float2 c = cspar[(size_t)t*256 + ((n>>1) & 255)];
          float r = (r16 & 1) ? (v*c.x + vp*c.y) : (v*c.x - vp*c.y);
          us hi, lo; splitf(r, hi, lo);
          Ch[(size_t)m*ldc + n] = hi;
          Cl[(size_t)m*ldc + n] = lo;
        } else {
          unsafeAtomicAdd(&C[(size_t)m*ldc + n], v);
        }
      }
    }
  }
}

// ---------------------------------------------------------------------------
// Row softmax on raw S ([H][T][T] f32 per batch): scale + causal mask +
// normalize, overwrite row with fp16 hi plane (first 2KB) + lo plane.
// Only cols < (t|127)+1 are touched (PV never reads past the causal tile).
// ---------------------------------------------------------------------------
__global__ void softmax_pk(float* __restrict__ S)
{
  const int row = blockIdx.x;          // h*T + t
  const int t = row & (T_-1);
  const int ncol = (t | 127) + 1;
  float* sr = S + (size_t)row*T_;
  const int tid = threadIdx.x;
  const int wid = tid >> 6, lane = tid & 63;
  __shared__ float red[8];
  const float scale = 0.044194173824159216f;  // 1/sqrt(512)
  const int c0 = tid*4;
  const bool act = (c0 < ncol);
  float a[4] = {-1e30f,-1e30f,-1e30f,-1e30f};
  if (act) {
    float4 v = ((const float4*)sr)[tid];
    a[0] = (c0+0 <= t) ? v.x*scale : -1e30f;
    a[1] = (c0+1 <= t) ? v.y*scale : -1e30f;
    a[2] = (c0+2 <= t) ? v.z*scale : -1e30f;
    a[3] = (c0+3 <= t) ? v.w*scale : -1e30f;
  }
  float mx = fmaxf(fmaxf(a[0],a[1]), fmaxf(a[2],a[3]));
  #pragma unroll
  for (int m=1; m<64; m<<=1) mx = fmaxf(mx, __shfl_xor(mx, m));
  if (lane == 0) red[wid] = mx;
  __syncthreads();
  mx = fmaxf(fmaxf(red[0],red[1]), fmaxf(red[2],red[3]));
  float p[4];
  float ps = 0.f;
  #pragma unroll
  for (int i=0;i<4;i++) { p[i] = expf(a[i] - mx); ps += p[i]; }
  #pragma unroll
  for (int m=1; m<64; m<<=1) ps += __shfl_xor(ps, m);
  __syncthreads();
  if (lane == 0) red[4+wid] = ps;
  __syncthreads();
  float l = red[4]+red[5]+red[6]+red[7];
  if (act) {
    ushort4 hiv, lov;
    us h0,l0,h1,l1,h2,l2,h3,l3;
    splitf(p[0]/l, h0, l0); splitf(p[1]/l, h1, l1);
    splitf(p[2]/l, h2, l2); splitf(p[3]/l, h3, l3);
    hiv.x=h0; hiv.y=h1; hiv.z=h2; hiv.w=h3;
    lov.x=l0; lov.y=l1; lov.z=l2; lov.w=l3;
    us* oh = (us*)sr;
    *(ushort4*)(oh + c0)        = hiv;
    *(ushort4*)(oh + 1024 + c0) = lov;
  }
}

// ---------------------------------------------------------------------------
// Sparse MoE w13 GEMM: per expert, gathered A rows (tok_idx), B = interleaved
// w1/w3 rows. Fused SiLU epilogue via shfl_xor(1).
// ---------------------------------------------------------------------------
__global__ __launch_bounds__(256, 2) void moe_w13(
    const us* __restrict__ xn2b, const us* __restrict__ w13b,
    const int* __restrict__ cnt, const int* __restrict__ tok_idx,
    us* __restrict__ hb)
{
  const int e = blockIdx.z;
  const int ce = cnt[e];
  const int m0 = blockIdx.y*128, n0 = blockIdx.x*128;
  if (m0 >= ce) return;
  __shared__ char sm[32768];
  __shared__ int sidx[128];
  char* smA = sm;
  char* smB = sm + 16384;
  const int tid = threadIdx.x;
  if (tid < 128) sidx[tid] = tok_idx[e*NTOK + m0 + tid] & (NTOK-1);
  __syncthreads();
  const int wid = tid >> 6, lane = tid & 63;
  const int wy = wid >> 1, wx = wid & 1;
  const int r16 = lane & 15, g4 = lane >> 4;
  const us* Bm = w13b + (size_t)e*2*F_*D_;

  f32x4 acc[4][4];
  #pragma unroll
  for (int i=0;i<4;i++)
    #pragma unroll
    for(int j=0;j<4;j++) acc[i][j] = (f32x4)0.f;

  for (int kt = 0; kt < 8; ++kt) {
    #pragma unroll
    for (int r = 0; r < 4; ++r) {
      int linear = r*256 + tid;
      int row = linear >> 3, ss = linear & 7;
      int sg = ss ^ (row & 7);
      int arow = sidx[row];
      __builtin_amdgcn_global_load_lds(
        (const __attribute__((address_space(1))) void*)(xn2b + (size_t)arow*D_ + kt*64 + sg*8),
        (__attribute__((address_space(3))) void*)(smA + linear*16), 16, 0, 0);
      __builtin_amdgcn_global_load_lds(
        (const __attribute__((address_space(1))) void*)(Bm + (size_t)(n0+row)*D_ + kt*64 + sg*8),
        (__attribute__((address_space(3))) void*)(smB + linear*16), 16, 0, 0);
    }
    __syncthreads();
    #pragma unroll
    for (int kk = 0; kk < 2; ++kk) {
      bf16x8 af[4], bfr[4];
      #pragma unroll
      for (int i=0;i<4;i++){
        int row = wy*64 + i*16 + r16;
        int sl = ((kk<<2) | g4) ^ (row & 7);
        af[i] = *(const bf16x8*)(smA + row*128 + sl*16);
      }
      #pragma unroll
      for (int j=0;j<4;j++){
        int row = wx*64 + j*16 + r16;
        int sl = ((kk<<2) | g4) ^ (row & 7);
        bfr[j] = *(const bf16x8*)(smB + row*128 + sl*16);
      }
      #pragma unroll
      for (int i=0;i<4;i++)
        #pragma unroll
        for (int j=0;j<4;j++)
          acc[i][j] = __builtin_amdgcn_mfma_f32_16x16x32_bf16(af[i], bfr[j], acc[i][j], 0,0,0);
    }
    __syncthreads();
  }

  #pragma unroll
  for (int i=0;i<4;i++) {
    #pragma unroll
    for (int reg=0; reg<4; ++reg) {
      int m = m0 + wy*64 + i*16 + g4*4 + reg;
      #pragma unroll
      for (int j=0;j<4;j++) {
        int n = n0 + wx*64 + j*16 + r16;
        float v = acc[i][j][reg];
        float vp = __shfl_xor(v, 1);
        if (!(r16 & 1)) {   // even lane: v = h1, vp = h3
          float hv = v / (1.f + __expf(-v)) * vp;
          hb[((size_t)e*NTOK + m)*F_ + (n>>1)] = f2b(hv);
        }
      }
    }
  }
}

// ---------------------------------------------------------------------------
// Sparse MoE w2 GEMM: A = hb (per-expert slots, K=F), B = w2b[e].
// Epilogue scatter: out[tok*D + n] += gate * v.
// ---------------------------------------------------------------------------
__global__ __launch_bounds__(256, 2) void moe_w2(
    const us* __restrict__ hb, const us* __restrict__ w2b,
    const int* __restrict__ cnt, const int* __restrict__ tok_idx,
    const float* __restrict__ tok_gate, float* __restrict__ out)
{
  const int e = blockIdx.z;
  const int ce = cnt[e];
  const int m0 = blockIdx.y*128, n0 = blockIdx.x*128;
  if (m0 >= ce) return;
  __shared__ char sm[32768];
  char* smA = sm;
  char* smB = sm + 16384;
  const int tid = threadIdx.x;
  const int wid = tid >> 6, lane = tid & 63;
  const int wy = wid >> 1, wx = wid & 1;
  const int r16 = lane & 15, g4 = lane >> 4;
  const us* Am = hb  + (size_t)e*NTOK*F_;
  const us* Bm = w2b + (size_t)e*D_*F_;

  f32x4 acc[4][4];
  #pragma unroll
  for (int i=0;i<4;i++)
    #pragma unroll
    for(int j=0;j<4;j++) acc[i][j] = (f32x4)0.f;

  for (int kt = 0; kt < 16; ++kt) {
    #pragma unroll
    for (int r = 0; r < 4; ++r) {
      int linear = r*256 + tid;
      int row = linear >> 3, ss = linear & 7;
      int sg = ss ^ (row & 7);
      __builtin_amdgcn_global_load_lds(
        (const __attribute__((address_space(1))) void*)(Am + (size_t)(m0+row)*F_ + kt*64 + sg*8),
        (__attribute__((address_space(3))) void*)(smA + linear*16), 16, 0, 0);
      __builtin_amdgcn_global_load_lds(
        (const __attribute__((address_space(1))) void*)(Bm + (size_t)(n0+row)*F_ + kt*64 + sg*8),
        (__attribute__((address_space(3))) void*)(smB + linear*16), 16, 0, 0);
    }
    __syncthreads();
    #pragma unroll
    for (int kk = 0; kk < 2; ++kk) {
      bf16x8 af[4], bfr[4];
      #pragma unroll
      for (int i=0;i<4;i++){
        int row = wy*64 + i*16 + r16;
        int sl = ((kk<<2) | g4) ^ (row & 7);
        af[i] = *(const bf16x8*)(smA + row*128 + sl*16);
      }
      #pragma unroll
      for (int j=0;j<4;j++){
        int row = wx*64 + j*16 + r16;
        int sl = ((kk<<2) | g4) ^ (row & 7);
        bfr[j] = *(const bf16x8*)(smB + row*128 + sl*16);
      }
      #pragma unroll
      for (int i=0;i<4;i++)
        #pragma unroll
        for (int j=0;j<4;j++)
          acc[i][j] = __builtin_amdgcn_mfma_f32_16x16x32_bf16(af[i], bfr[j], acc[i][j], 0,0,0);
    }
    __syncthreads();
  }

  #pragma unroll
  for (int i=0;i<4;i++) {
    #pragma unroll
    for (int reg=0; reg<4; ++reg) {
      int m = m0 + wy*64 + i*16 + g4*4 + reg;
      if (m < ce) {
        int tok = tok_idx[e*NTOK + m] & (NTOK-1);
        float g = tok_gate[e*NTOK + m];
        #pragma unroll
        for (int j=0;j<4;j++) {
          int n = n0 + wx*64 + j*16 + r16;
          unsafeAtomicAdd(&out[(size_t)tok*D_ + n], g * acc[i][j][reg]);
        }
      }
    }
  }
}

// ---------------------------------------------------------------------------
// RoPE cos/sin table (f64 pow -> correctly-rounded f32 inv_freq)
// ---------------------------------------------------------------------------
__global__ void rope_table(const int* __restrict__ pos, float2* __restrict__ cs)
{
  int idx = blockIdx.x*256 + threadIdx.x;   // T*256
  int t = idx >> 8, j = idx & 255;
  float xj = (float)j * (1.0f/256.0f);
  float p32 = (float)pow(10000.0, (double)xj);
  float invf = 1.0f / p32;
  float ang = (float)pos[t] * invf;
  cs[idx] = make_float2(cosf(ang), sinf(ang));
}

// ---------------------------------------------------------------------------
// LN1 (two-pass var) -> xn1 fp16 hi/lo planes + roped K planes (interleaved)
// ---------------------------------------------------------------------------
__global__ void ln1_kernel(const float* __restrict__ x, const float* __restrict__ g,
    const float* __restrict__ be, const float2* __restrict__ cs,
    us* __restrict__ xn1h, us* __restrict__ xn1l,
    us* __restrict__ Krh, us* __restrict__ Krl)
{
  const int row = blockIdx.x;           // b*T + t
  const int t = row & (T_-1);
  const int tid = threadIdx.x;
  __shared__ float red[8];
  float v0 = x[(size_t)row*D_ + tid];
  float v1 = x[(size_t)row*D_ + 256 + tid];
  const int wid = tid>>6, lane = tid&63;
  float s = v0 + v1;
  #pragma unroll
  for (int m=1; m<64; m<<=1) s += __shfl_xor(s,m);
  if (lane == 0) red[wid] = s;
  __syncthreads();
  s = red[0]+red[1]+red[2]+red[3];
  float mu = s * (1.f/D_);
  float d0 = v0-mu, d1 = v1-mu;
  float q = d0*d0 + d1*d1;
  #pragma unroll
  for (int m=1; m<64; m<<=1) q += __shfl_xor(q,m);
  __syncthreads();
  if (lane == 0) red[wid] = q;
  __syncthreads();
  q = red[0]+red[1]+red[2]+red[3];
  float var = q * (1.f/D_);
  float rs = rsqrtf(var + 1e-5f);
  float n0 = d0*rs*g[tid]     + be[tid];
  float n1 = d1*rs*g[tid+256] + be[tid+256];
  splitf(n0, xn1h[(size_t)row*D_ + tid],       xn1l[(size_t)row*D_ + tid]);
  splitf(n1, xn1h[(size_t)row*D_ + 256 + tid], xn1l[(size_t)row*D_ + 256 + tid]);
  float2 c = cs[(size_t)t*256 + tid];
  float k0 = n0*c.x - n1*c.y;
  float k1 = n1*c.x + n0*c.y;
  us k0h,k0l,k1h,k1l;
  splitf(k0, k0h, k0l);
  splitf(k1, k1h, k1l);
  size_t kb = (size_t)row*D_ + 2*tid;
  *(unsigned*)(Krh + kb) = (unsigned)k0h | ((unsigned)k1h << 16);
  *(unsigned*)(Krl + kb) = (unsigned)k0l | ((unsigned)k1l << 16);
}

// ---------------------------------------------------------------------------
// Transpose-split: f32 (R,C) -> fp16 hi/lo planes (C,R). ROPE variant permutes
// dest rows so RoPE pairs are adjacent cols in the Q-GEMM output.
// ---------------------------------------------------------------------------
template<int ROPE>
__global__ void transpose_split(const float* __restrict__ in,
    us* __restrict__ outh, us* __restrict__ outl, int R, int C)
{
  __shared__ float tile[32][33];
  const int c0 = blockIdx.x*32, r0 = blockIdx.y*32;
  const int tc = threadIdx.x & 31, tr = threadIdx.x >> 5;  // tr in 0..7
  #pragma unroll
  for (int i=0;i<4;i++)
    tile[tr + 8*i][tc] = in[(size_t)(r0 + tr + 8*i)*C + c0 + tc];
  __syncthreads();
  #pragma unroll
  for (int i=0;i<4;i++) {
    float v = tile[tc][tr + 8*i];
    int j0 = c0 + tr + 8*i;
    int n = j0;
    if (ROPE) {
      int jh = j0 & 511;
      n = (j0 & ~511) | ((jh & 255) << 1) | (jh >> 8);
    }
    size_t o = (size_t)n*R + r0 + tc;
    splitf(v, outh[o], outl[o]);
  }
}

// cast f32 -> bf16, 4 elems/thread
__global__ void cast_bf16(const float* __restrict__ in, us* __restrict__ out, int n4)
{
  int i = blockIdx.x*256 + threadIdx.x;
  if (i >= n4) return;
  float4 v = ((const float4*)in)[i];
  union { us u[4]; uint2 v2; } r;
  r.u[0]=f2b(v.x); r.u[1]=f2b(v.y); r.u[2]=f2b(v.z); r.u[3]=f2b(v.w);
  ((uint2*)out)[i] = r.v2;
}

// cast w1/w3 (E,F,D) f32 into w13b (E, 2F, D) bf16, dest row 2f+par
__global__ void cast_w13(const float* __restrict__ in, us* __restrict__ out, int par)
{
  int i = blockIdx.x*256 + threadIdx.x;   // E*F*D/4
  int e = i / (F_*D_/4);
  int rem = i - e*(F_*D_/4);
  int f = rem / (D_/4);
  int d4 = rem - f*(D_/4);
  float4 v = ((const float4*)in)[i];
  union { us u[4]; uint2 v2; } r;
  r.u[0]=f2b(v.x); r.u[1]=f2b(v.y); r.u[2]=f2b(v.z); r.u[3]=f2b(v.w);
  size_t ob = (size_t)e*(2*F_*D_/4) + (size_t)(2*f+par)*(D_/4) + d4;
  ((uint2*)out)[ob] = r.v2;
}

// ---------------------------------------------------------------------------
// x1 = x + Obsum; out = x1 (f32); xn2b = bf16(LN2(x1)); fused router logits
// logits[row*8+e] = xn2 . rw[e]  (f32)
// ---------------------------------------------------------------------------
__global__ void resid_ln2_kernel(const float* __restrict__ x, const float* __restrict__ Obsum,
    const float* __restrict__ g, const float* __restrict__ be,
    const float* __restrict__ rw,
    float* __restrict__ out, us* __restrict__ xn2b, float* __restrict__ logits)
{
  const int row = blockIdx.x;
  const int tid = threadIdx.x;
  __shared__ float red[8];
  __shared__ float red2[4][8];
  float a0 = x[(size_t)row*D_ + tid]       + Obsum[(size_t)row*D_ + tid];
  float a1 = x[(size_t)row*D_ + 256 + tid] + Obsum[(size_t)row*D_ + 256 + tid];
  out[(size_t)row*D_ + tid] = a0;
  out[(size_t)row*D_ + 256 + tid] = a1;
  const int wid = tid>>6, lane = tid&63;
  float s = a0 + a1;
  #pragma unroll
  for (int m=1; m<64; m<<=1) s += __shfl_xor(s,m);
  if (lane == 0) red[wid] = s;
  __syncthreads();
  s = red[0]+red[1]+red[2]+red[3];
  float mu = s * (1.f/D_);
  float d0 = a0-mu, d1 = a1-mu;
  float q = d0*d0 + d1*d1;
  #pragma unroll
  for (int m=1; m<64; m<<=1) q += __shfl_xor(q,m);
  __syncthreads();
  if (lane == 0) red[wid] = q;
  __syncthreads();
  q = red[0]+red[1]+red[2]+red[3];
  float var = q * (1.f/D_);
  float rs = rsqrtf(var + 1e-5f);
  float n0 = d0*rs*g[tid]     + be[tid];
  float n1 = d1*rs*g[tid+256] + be[tid+256];
  xn2b[(size_t)row*D_ + tid]       = f2b(n0);
  xn2b[(size_t)row*D_ + 256 + tid] = f2b(n1);
  // fused router logits
  float pl[8];
  #pragma unroll
  for (int e=0;e<E_;e++)
    pl[e] = n0*rw[e*D_ + tid] + n1*rw[e*D_ + 256 + tid];
  #pragma unroll
  for (int m=1; m<64; m<<=1)
    #pragma unroll
    for (int e=0;e<E_;e++) pl[e] += __shfl_xor(pl[e], m);
  if (lane == 0)
    #pragma unroll
    for (int e=0;e<E_;e++) red2[wid][e] = pl[e];
  __syncthreads();
  if (tid < 8)
    logits[(size_t)row*8 + tid] = red2[0][tid]+red2[1][tid]+red2[2][tid]+red2[3][tid];
}

// ---------------------------------------------------------------------------
// Router compaction: single block, deterministic, no global atomics.
// 1024 threads x 4 tokens: top-2 + gates, 8-vector Hillis-Steele prefix scan
// in LDS assigns slots in token order.
// ---------------------------------------------------------------------------
__global__ __launch_bounds__(1024) void router_compact(
    const float* __restrict__ logits, int* __restrict__ cnt,
    int* __restrict__ tok_idx, float* __restrict__ tok_gate)
{
  const int tid = threadIdx.x;
  __shared__ int sc[1024][8];
  int e1v[4], e2v[4];
  float g1v[4], g2v[4];
  int lc[8] = {0,0,0,0,0,0,0,0};
  #pragma unroll
  for (int i=0;i<4;i++) {
    int tok = tid*4 + i;
    float lg[8];
    float4 a = *(const float4*)(logits + (size_t)tok*8);
    float4 b = *(const float4*)(logits + (size_t)tok*8 + 4);
    lg[0]=a.x; lg[1]=a.y; lg[2]=a.z; lg[3]=a.w;
    lg[4]=b.x; lg[5]=b.y; lg[6]=b.z; lg[7]=b.w;
    int i1 = 0;
    #pragma unroll
    for (int e=1;e<E_;e++) if (lg[e] > lg[i1]) i1 = e;
    int i2 = (i1==0) ? 1 : 0;
    #pragma unroll
    for (int e=0;e<E_;e++) if (e != i1 && lg[e] > lg[i2]) i2 = e;
    float p2 = expf(lg[i2] - lg[i1]);
    float den = 1.f + p2;
    e1v[i] = i1; g1v[i] = 1.f/den;
    e2v[i] = i2; g2v[i] = p2/den;
    lc[i1]++; lc[i2]++;
  }
  #pragma unroll
  for (int e=0;e<E_;e++) sc[tid][e] = lc[e];
  __syncthreads();
  for (int off=1; off<1024; off<<=1) {
    int tmp[8];
    if (tid >= off) {
      #pragma unroll
      for (int e=0;e<E_;e++) tmp[e] = sc[tid-off][e];
    }
    __syncthreads();
    if (tid >= off) {
      #pragma unroll
      for (int e=0;e<E_;e++) sc[tid][e] += tmp[e];
    }
    __syncthreads();
  }
  int run[8];
  #pragma unroll
  for (int e=0;e<E_;e++) run[e] = sc[tid][e] - lc[e];   // exclusive prefix
  if (tid == 0) {
    #pragma unroll
    for (int e=0;e<E_;e++) cnt[e] = sc[1023][e];
  }
  #pragma unroll
  for (int i=0;i<4;i++) {
    int tok = tid*4 + i;
    int s1 = run[e1v[i]]++;
    tok_idx[e1v[i]*NTOK + s1]  = tok;
    tok_gate[e1v[i]*NTOK + s1] = g1v[i];
    int s2 = run[e2v[i]]++;
    tok_idx[e2v[i]*NTOK + s2]  = tok;
    tok_gate[e2v[i]*NTOK + s2] = g2v[i];
  }
}

// ---------------------------------------------------------------------------
extern "C" void kernel_launch(void* const* d_in, const int* in_sizes, int n_in,
                              void* d_out, int out_size, void* d_ws, size_t ws_size,
                              hipStream_t stream)
{
  const float* x    = (const float*)d_in[0];
  const int*   pos  = (const int*)d_in[1];
  const float* ln1g = (const float*)d_in[2];
  const float* ln1b = (const float*)d_in[3];
  const float* M    = (const float*)d_in[4];
  const float* V    = (const float*)d_in[5];
  const float* ln2g = (const float*)d_in[6];
  const float* ln2b = (const float*)d_in[7];
  const float* rw   = (const float*)d_in[8];
  const float* w1   = (const float*)d_in[9];
  const float* w2   = (const float*)d_in[10];
  const float* w3   = (const float*)d_in[11];
  float* out = (float*)d_out;

  char* ws = (char*)d_ws;
  const size_t MB = (size_t)1 << 20;
  // --- persistent across attention phase ---
  float2* cs  = (float2*)(ws + 0);            // 2MB
  us* Krh  = (us*)(ws + 2*MB);                // 4MB  (interleaved pair order)
  us* Krl  = (us*)(ws + 6*MB);                // 4MB
  us* valTh   = (us*)(ws + 10*MB);            // 32MB (10..42)
  us* valTl   = (us*)(ws + 42*MB);            // 32MB (42..74)
  us* Qhp     = (us*)(ws + 74*MB);            // 32MB (74..106, roped+interleaved)
  us* Qlp     = (us*)(ws + 106*MB);           // 32MB (106..138)
  float* S    = (float*)(ws + 138*MB);        // 32MB per-batch scores (P in place)
  // projection-phase temporaries overlay the S region (dead before S written)
  us* xn1h = (us*)(ws + 138*MB);              // 4MB
  us* xn1l = (us*)(ws + 142*MB);              // 4MB
  us* Mth  = (us*)(ws + 146*MB);              // 8MB
  us* Mtl  = (us*)(ws + 154*MB);              // 8MB
  us* Vth  = (us*)(ws + 162*MB);              // 8MB
  us* Vtl  = (us*)(ws + 170*MB);              // 8MB (ends 178)
  float* Obsum = (float*)(ws + 180*MB);       // 8MB
  float* logits = (float*)(ws + 188*MB);      // 128KB
  us* xn2b     = (us*)(ws + 196*MB);          // 4MB
  int*   cnt      = (int*)  (ws + 200*MB);              // 32B
  int*   tok_idx  = (int*)  (ws + 200*MB + 4096);       // 128KB
  float* tok_gate = (float*)(ws + 200*MB + 4096 + 128*1024); // 128KB
  // MoE temporaries overlay attention-dead regions
  us* w13b = (us*)(ws + 10*MB);               // 16MB (over valTh, dead post-attn)
  us* w2b  = (us*)(ws + 26*MB);               // 8MB  (26..34)
  us* hb   = (us*)(ws + 74*MB);               // 64MB (over Qhp/Qlp, 74..138)

  rope_table<<<T_, 256, 0, stream>>>(pos, cs);
  ln1_kernel<<<NTOK, 256, 0, stream>>>(x, ln1g, ln1b, cs, xn1h, xn1l, Krh, Krl);
  transpose_split<1><<<dim3(HD/32, D_/32), 256, 0, stream>>>(M, Mth, Mtl, D_, HD);
  transpose_split<0><<<dim3(HD/32, D_/32), 256, 0, stream>>>(V, Vth, Vtl, D_, HD);

  // Q = rope(xn1 @ M) fused epilogue -> Qhp/Qlp (interleaved pair order)
  gemm_ms<4><<<dim3(HD/128, NTOK/128, 1), 256, 0, stream>>>(
      xn1h, xn1l, Mth, Mtl, nullptr, Qhp, Qlp,
      NTOK, HD, D_, D_, D_, HD, 0, 0, 0, cs);
  // valT[h,d,b,t] = V^T @ xn1^T, split store
  gemm_ms<1><<<dim3(NTOK/128, HD/128, 1), 256, 0, stream>>>(
      Vth, Vtl, xn1h, xn1l, nullptr, valTh, valTl,
      HD, NTOK, D_, D_, D_, NTOK, 0, 0, 0, nullptr);

  hipMemsetAsync(Obsum, 0, (size_t)NTOK*D_*sizeof(float), stream);

  // --- attention: per batch, S-GEMM (causal tiles) -> softmax -> PV ---
  for (int b = 0; b < B_; ++b) {
    gemm_ms<2><<<dim3(T_/128, T_/128, H_), 256, 0, stream>>>(
        Qhp + (size_t)b*T_*HD, Qlp + (size_t)b*T_*HD,
        Krh + (size_t)b*T_*D_, Krl + (size_t)b*T_*D_,
        S, nullptr, nullptr,
        T_, T_, D_, HD, D_, T_,
        (long)D_, 0, (long)T_*T_, nullptr);
    softmax_pk<<<H_*T_, 256, 0, stream>>>(S);
    gemm_ms<3><<<dim3(D_/128, T_/128, H_), 256, 0, stream>>>(
        (const us*)S, (const us*)S + 1024,
        valTh + (size_t)b*T_, valTl + (size_t)b*T_,
        Obsum + (size_t)b*T_*D_, nullptr, nullptr,
        T_, D_, T_, 2048, NTOK, D_,
        (long)T_*2048, (long)D_*NTOK, 0, nullptr);
  }

  resid_ln2_kernel<<<NTOK, 256, 0, stream>>>(x, Obsum, ln2g, ln2b, rw, out, xn2b, logits);
  router_compact<<<1, 1024, 0, stream>>>(logits, cnt, tok_idx, tok_gate);

  // MoE weights (regions freed after attention)
  cast_w13<<<(E_*F_*D_/4)/256, 256, 0, stream>>>(w1, w13b, 0);
  cast_w13<<<(E_*F_*D_/4)/256, 256, 0, stream>>>(w3, w13b, 1);
  cast_bf16<<<(E_*D_*F_/4)/256, 256, 0, stream>>>(w2, w2b, E_*D_*F_/4);

  // Sparse MoE: gathered w13 GEMM (fused silu) then w2 GEMM (scatter-add)
  moe_w13<<<dim3(2*F_/128, NTOK/128, E_), 256, 0, stream>>>(
      xn2b, w13b, cnt, tok_idx, hb);
  moe_w2<<<dim3(D_/128, NTOK/128, E_), 256, 0, stream>>>(
      hb, w2b, cnt, tok_idx, tok_gate, out);
}

// Round 7
// 470.192 us; speedup vs baseline: 3.7679x; 1.1397x over previous
//
#include <hip/hip_runtime.h>
#include <cstdint>
#include <cstddef>
#include <math.h>

#define B_ 4
#define T_ 1024
#define D_ 512
#define H_ 8
#define E_ 8
#define F_ 1024
#define NTOK (B_*T_)   // 4096
#define HD   (H_*D_)   // 4096
#define PACKF (36*16384)   // f32 per packed causal S slice (36 tiles of 128x128)

typedef float f32x4 __attribute__((ext_vector_type(4)));
typedef short bf16x8 __attribute__((ext_vector_type(8)));
typedef _Float16 f16x8 __attribute__((ext_vector_type(8)));
typedef unsigned short us;

union H16 { _Float16 h; unsigned short u; };

__device__ __forceinline__ us f2b(float f){
  union { float f; unsigned u; } v; v.f = f;
  unsigned r = v.u + 0x7fffu + ((v.u >> 16) & 1u);
  return (us)(r >> 16);
}
__device__ __forceinline__ float b2f(us h){
  union { unsigned u; float f; } v; v.u = ((unsigned)h) << 16; return v.f;
}
__device__ __forceinline__ void splitf(float x, us& hi, us& lo){
  H16 a, b;
  a.h = (_Float16)x;
  b.h = (_Float16)(x - (float)a.h);
  hi = a.u; lo = b.u;
}

// ---------------------------------------------------------------------------
// fp16-split GEMM (3-product Markidis, ~f32). 128x128 tile, BK=64, 4 waves.
// MODE 1: generic, split hi/lo store.
// MODE 4: generic, RoPE epilogue (interleaved pair cols) + split store.
// MODE 2: attention S: A=Q[b,t,h*D], B=Kr[b,k,:], C=packed causal S slice z.
//         skip tiles bx>by. z = (b-bbase)*8+h.
// MODE 5: attention PV: A=packed P planes (Ah = (us*)S base), B=valT planes,
//         C=Obsum atomic-add. K limited to m0+128.
// ---------------------------------------------------------------------------
template<int MODE>
__global__ __launch_bounds__(256, 2) void gemm_ms(
    const us* __restrict__ Ah, const us* __restrict__ Al,
    const us* __restrict__ Bh, const us* __restrict__ Bl,
    float* __restrict__ C, us* __restrict__ Ch, us* __restrict__ Cl,
    int M, int N, int K, int lda, int ldb, int ldc,
    const float2* __restrict__ cspar, int bbase)
{
  if (MODE == 2 && blockIdx.x > blockIdx.y) return;
  const int z = blockIdx.z;
  const int zb = bbase + (z >> 3), zh = z & 7;
  if (MODE == 2) {
    Ah += (size_t)zb*T_*HD + (size_t)zh*D_;
    Al += (size_t)zb*T_*HD + (size_t)zh*D_;
    Bh += (size_t)zb*T_*D_;
    Bl += (size_t)zb*T_*D_;
    C  += (size_t)z*PACKF;
  } else if (MODE == 5) {
    Bh += (size_t)zh*D_*NTOK + (size_t)zb*T_;
    Bl += (size_t)zh*D_*NTOK + (size_t)zb*T_;
    C  += (size_t)zb*T_*D_;
  }

  __shared__ char sm[65536];
  char* sAh = sm;
  char* sAl = sm + 16384;
  char* sBh = sm + 32768;
  char* sBl = sm + 49152;
  const int tid = threadIdx.x;
  const int m0 = blockIdx.y*128, n0 = blockIdx.x*128;
  const int wid = tid >> 6, lane = tid & 63;
  const int wy = wid >> 1, wx = wid & 1;
  const int r16 = lane & 15, g4 = lane >> 4;

  f32x4 acc[4][4];
  #pragma unroll
  for (int i=0;i<4;i++)
    #pragma unroll
    for(int j=0;j<4;j++) acc[i][j] = (f32x4)0.f;

  int nkt = K >> 6;
  if (MODE == 5) nkt = (m0 + 128) >> 6;
  // packed-P tile base (per-z, per-block-row) for MODE 5
  const size_t ztri = (MODE == 5) ? ((size_t)z*36 + (size_t)(m0>>7)*((m0>>7)+1)/2) : 0;

  for (int kt = 0; kt < nkt; ++kt) {
    #pragma unroll
    for (int r = 0; r < 4; ++r) {
      int linear = r*256 + tid;
      int row = linear >> 3, ss = linear & 7;
      int sg = ss ^ (row & 7);
      if (MODE == 5) {
        size_t tb = (ztri + (kt>>1))*32768;
        int kc = ((kt&1)<<6) | (sg*8);
        __builtin_amdgcn_global_load_lds(
          (const __attribute__((address_space(1))) void*)(Ah + tb + row*256 + kc),
          (__attribute__((address_space(3))) void*)(sAh + linear*16), 16, 0, 0);
        __builtin_amdgcn_global_load_lds(
          (const __attribute__((address_space(1))) void*)(Ah + tb + row*256 + 128 + kc),
          (__attribute__((address_space(3))) void*)(sAl + linear*16), 16, 0, 0);
      } else {
        size_t ga = (size_t)(m0+row)*lda + kt*64 + sg*8;
        __builtin_amdgcn_global_load_lds((const __attribute__((address_space(1))) void*)(Ah + ga),
          (__attribute__((address_space(3))) void*)(sAh + linear*16), 16, 0, 0);
        __builtin_amdgcn_global_load_lds((const __attribute__((address_space(1))) void*)(Al + ga),
          (__attribute__((address_space(3))) void*)(sAl + linear*16), 16, 0, 0);
      }
      size_t gb = (size_t)(n0+row)*ldb + kt*64 + sg*8;
      __builtin_amdgcn_global_load_lds((const __attribute__((address_space(1))) void*)(Bh + gb),
        (__attribute__((address_space(3))) void*)(sBh + linear*16), 16, 0, 0);
      __builtin_amdgcn_global_load_lds((const __attribute__((address_space(1))) void*)(Bl + gb),
        (__attribute__((address_space(3))) void*)(sBl + linear*16), 16, 0, 0);
    }
    __syncthreads();
    #pragma unroll
    for (int kk = 0; kk < 2; ++kk) {
      f16x8 ah[4], al[4], bh[4], bl[4];
      #pragma unroll
      for (int i=0;i<4;i++){
        int row = wy*64 + i*16 + r16;
        int sl = ((kk<<2) | g4) ^ (row & 7);
        ah[i] = *(const f16x8*)(sAh + row*128 + sl*16);
        al[i] = *(const f16x8*)(sAl + row*128 + sl*16);
      }
      #pragma unroll
      for (int j=0;j<4;j++){
        int row = wx*64 + j*16 + r16;
        int sl = ((kk<<2) | g4) ^ (row & 7);
        bh[j] = *(const f16x8*)(sBh + row*128 + sl*16);
        bl[j] = *(const f16x8*)(sBl + row*128 + sl*16);
      }
      #pragma unroll
      for (int i=0;i<4;i++)
        #pragma unroll
        for (int j=0;j<4;j++) {
          acc[i][j] = __builtin_amdgcn_mfma_f32_16x16x32_f16(ah[i], bh[j], acc[i][j], 0,0,0);
          acc[i][j] = __builtin_amdgcn_mfma_f32_16x16x32_f16(ah[i], bl[j], acc[i][j], 0,0,0);
          acc[i][j] = __builtin_amdgcn_mfma_f32_16x16x32_f16(al[i], bh[j], acc[i][j], 0,0,0);
        }
    }
    __syncthreads();
  }

  const int tidx = (MODE == 2) ? (blockIdx.y*(blockIdx.y+1)/2 + blockIdx.x) : 0;
  #pragma unroll
  for (int i=0;i<4;i++) {
    #pragma unroll
    for (int reg=0; reg<4; ++reg) {
      int lm = wy*64 + i*16 + g4*4 + reg;
      int m = m0 + lm;
      int t = m & (T_-1);
      #pragma unroll
      for (int j=0;j<4;j++) {
        int ln = wx*64 + j*16 + r16;
        int n = n0 + ln;
        float v = acc[i][j][reg];
        if (MODE == 2) {
          C[(size_t)tidx*16384 + lm*128 + ln] = v;
        } else if (MODE == 1) {
          us hi, lo; splitf(v, hi, lo);
          Ch[(size_t)m*ldc + n] = hi;
          Cl[(size_t)m*ldc + n] = lo;
        } else if (MODE == 4) {
          float vp = __shfl_xor(v, 1);
          float2 c = cspar[(size_t)t*256 + ((n>>1) & 255)];
          float r = (r16 & 1) ? (v*c.x + vp*c.y) : (v*c.x - vp*c.y);
          us hi, lo; splitf(r, hi, lo);
          Ch[(size_t)m*ldc + n] = hi;
          Cl[(size_t)m*ldc + n] = lo;
        } else {  // MODE 5
          unsafeAtomicAdd(&C[(size_t)m*ldc + n], v);
        }
      }
    }
  }
}

// ---------------------------------------------------------------------------
// Row softmax on packed causal S (z slices of 36 tiles): scale + mask +
// normalize; overwrite each 128-f32 row segment with 128 hi + 128 lo fp16.
// blockIdx.x = z*T + t.
// ---------------------------------------------------------------------------
__global__ void softmax_pk(float* __restrict__ S)
{
  const int row = blockIdx.x;
  const int z = row >> 10, t = row & (T_-1);
  const int ty = t >> 7;
  const int tri = ty*(ty+1)/2;
  const int ncol = (ty+1)*128;
  float* Sz = S + (size_t)z*PACKF;
  const int tid = threadIdx.x;
  const int wid = tid >> 6, lane = tid & 63;
  __shared__ float red[8];
  const float scale = 0.044194173824159216f;  // 1/sqrt(512)
  const int c0 = tid*4;
  const bool act = (c0 < ncol);
  float* seg = Sz + (size_t)(tri + (c0>>7))*16384 + (t & 127)*128;
  float a[4] = {-1e30f,-1e30f,-1e30f,-1e30f};
  if (act) {
    float4 v = *(const float4*)(seg + (c0 & 127));
    a[0] = (c0+0 <= t) ? v.x*scale : -1e30f;
    a[1] = (c0+1 <= t) ? v.y*scale : -1e30f;
    a[2] = (c0+2 <= t) ? v.z*scale : -1e30f;
    a[3] = (c0+3 <= t) ? v.w*scale : -1e30f;
  }
  float mx = fmaxf(fmaxf(a[0],a[1]), fmaxf(a[2],a[3]));
  #pragma unroll
  for (int m=1; m<64; m<<=1) mx = fmaxf(mx, __shfl_xor(mx, m));
  if (lane == 0) red[wid] = mx;
  __syncthreads();
  mx = fmaxf(fmaxf(red[0],red[1]), fmaxf(red[2],red[3]));
  float p[4];
  float ps = 0.f;
  #pragma unroll
  for (int i=0;i<4;i++) { p[i] = expf(a[i] - mx); ps += p[i]; }
  #pragma unroll
  for (int m=1; m<64; m<<=1) ps += __shfl_xor(ps, m);
  __syncthreads();
  if (lane == 0) red[4+wid] = ps;
  __syncthreads();
  float l = red[4]+red[5]+red[6]+red[7];
  if (act) {
    ushort4 hiv, lov;
    us h0,l0,h1,l1,h2,l2,h3,l3;
    splitf(p[0]/l, h0, l0); splitf(p[1]/l, h1, l1);
    splitf(p[2]/l, h2, l2); splitf(p[3]/l, h3, l3);
    hiv.x=h0; hiv.y=h1; hiv.z=h2; hiv.w=h3;
    lov.x=l0; lov.y=l1; lov.z=l2; lov.w=l3;
    us* sp = (us*)seg;
    *(ushort4*)(sp + (c0 & 127))       = hiv;
    *(ushort4*)(sp + 128 + (c0 & 127)) = lov;
  }
}

// ---------------------------------------------------------------------------
// Sparse MoE w13 GEMM: gathered A rows, interleaved w1/w3, fused SiLU.
// ---------------------------------------------------------------------------
__global__ __launch_bounds__(256, 2) void moe_w13(
    const us* __restrict__ xn2b, const us* __restrict__ w13b,
    const int* __restrict__ cnt, const int* __restrict__ tok_idx,
    us* __restrict__ hb)
{
  const int e = blockIdx.z;
  const int ce = cnt[e];
  const int m0 = blockIdx.y*128, n0 = blockIdx.x*128;
  if (m0 >= ce) return;
  __shared__ char sm[32768];
  __shared__ int sidx[128];
  char* smA = sm;
  char* smB = sm + 16384;
  const int tid = threadIdx.x;
  if (tid < 128) sidx[tid] = tok_idx[e*NTOK + m0 + tid] & (NTOK-1);
  __syncthreads();
  const int wid = tid >> 6, lane = tid & 63;
  const int wy = wid >> 1, wx = wid & 1;
  const int r16 = lane & 15, g4 = lane >> 4;
  const us* Bm = w13b + (size_t)e*2*F_*D_;

  f32x4 acc[4][4];
  #pragma unroll
  for (int i=0;i<4;i++)
    #pragma unroll
    for(int j=0;j<4;j++) acc[i][j] = (f32x4)0.f;

  for (int kt = 0; kt < 8; ++kt) {
    #pragma unroll
    for (int r = 0; r < 4; ++r) {
      int linear = r*256 + tid;
      int row = linear >> 3, ss = linear & 7;
      int sg = ss ^ (row & 7);
      int arow = sidx[row];
      __builtin_amdgcn_global_load_lds(
        (const __attribute__((address_space(1))) void*)(xn2b + (size_t)arow*D_ + kt*64 + sg*8),
        (__attribute__((address_space(3))) void*)(smA + linear*16), 16, 0, 0);
      __builtin_amdgcn_global_load_lds(
        (const __attribute__((address_space(1))) void*)(Bm + (size_t)(n0+row)*D_ + kt*64 + sg*8),
        (__attribute__((address_space(3))) void*)(smB + linear*16), 16, 0, 0);
    }
    __syncthreads();
    #pragma unroll
    for (int kk = 0; kk < 2; ++kk) {
      bf16x8 af[4], bfr[4];
      #pragma unroll
      for (int i=0;i<4;i++){
        int row = wy*64 + i*16 + r16;
        int sl = ((kk<<2) | g4) ^ (row & 7);
        af[i] = *(const bf16x8*)(smA + row*128 + sl*16);
      }
      #pragma unroll
      for (int j=0;j<4;j++){
        int row = wx*64 + j*16 + r16;
        int sl = ((kk<<2) | g4) ^ (row & 7);
        bfr[j] = *(const bf16x8*)(smB + row*128 + sl*16);
      }
      #pragma unroll
      for (int i=0;i<4;i++)
        #pragma unroll
        for (int j=0;j<4;j++)
          acc[i][j] = __builtin_amdgcn_mfma_f32_16x16x32_bf16(af[i], bfr[j], acc[i][j], 0,0,0);
    }
    __syncthreads();
  }

  #pragma unroll
  for (int i=0;i<4;i++) {
    #pragma unroll
    for (int reg=0; reg<4; ++reg) {
      int m = m0 + wy*64 + i*16 + g4*4 + reg;
      #pragma unroll
      for (int j=0;j<4;j++) {
        int n = n0 + wx*64 + j*16 + r16;
        float v = acc[i][j][reg];
        float vp = __shfl_xor(v, 1);
        if (!(r16 & 1)) {   // even lane: v = h1, vp = h3
          float hv = v / (1.f + __expf(-v)) * vp;
          hb[((size_t)e*NTOK + m)*F_ + (n>>1)] = f2b(hv);
        }
      }
    }
  }
}

// ---------------------------------------------------------------------------
// Sparse MoE w2 GEMM: scatter-add epilogue out[tok*D+n] += gate*v.
// ---------------------------------------------------------------------------
__global__ __launch_bounds__(256, 2) void moe_w2(
    const us* __restrict__ hb, const us* __restrict__ w2b,
    const int* __restrict__ cnt, const int* __restrict__ tok_idx,
    const float* __restrict__ tok_gate, float* __restrict__ out)
{
  const int e = blockIdx.z;
  const int ce = cnt[e];
  const int m0 = blockIdx.y*128, n0 = blockIdx.x*128;
  if (m0 >= ce) return;
  __shared__ char sm[32768];
  char* smA = sm;
  char* smB = sm + 16384;
  const int tid = threadIdx.x;
  const int wid = tid >> 6, lane = tid & 63;
  const int wy = wid >> 1, wx = wid & 1;
  const int r16 = lane & 15, g4 = lane >> 4;
  const us* Am = hb  + (size_t)e*NTOK*F_;
  const us* Bm = w2b + (size_t)e*D_*F_;

  f32x4 acc[4][4];
  #pragma unroll
  for (int i=0;i<4;i++)
    #pragma unroll
    for(int j=0;j<4;j++) acc[i][j] = (f32x4)0.f;

  for (int kt = 0; kt < 16; ++kt) {
    #pragma unroll
    for (int r = 0; r < 4; ++r) {
      int linear = r*256 + tid;
      int row = linear >> 3, ss = linear & 7;
      int sg = ss ^ (row & 7);
      __builtin_amdgcn_global_load_lds(
        (const __attribute__((address_space(1))) void*)(Am + (size_t)(m0+row)*F_ + kt*64 + sg*8),
        (__attribute__((address_space(3))) void*)(smA + linear*16), 16, 0, 0);
      __builtin_amdgcn_global_load_lds(
        (const __attribute__((address_space(1))) void*)(Bm + (size_t)(n0+row)*F_ + kt*64 + sg*8),
        (__attribute__((address_space(3))) void*)(smB + linear*16), 16, 0, 0);
    }
    __syncthreads();
    #pragma unroll
    for (int kk = 0; kk < 2; ++kk) {
      bf16x8 af[4], bfr[4];
      #pragma unroll
      for (int i=0;i<4;i++){
        int row = wy*64 + i*16 + r16;
        int sl = ((kk<<2) | g4) ^ (row & 7);
        af[i] = *(const bf16x8*)(smA + row*128 + sl*16);
      }
      #pragma unroll
      for (int j=0;j<4;j++){
        int row = wx*64 + j*16 + r16;
        int sl = ((kk<<2) | g4) ^ (row & 7);
        bfr[j] = *(const bf16x8*)(smB + row*128 + sl*16);
      }
      #pragma unroll
      for (int i=0;i<4;i++)
        #pragma unroll
        for (int j=0;j<4;j++)
          acc[i][j] = __builtin_amdgcn_mfma_f32_16x16x32_bf16(af[i], bfr[j], acc[i][j], 0,0,0);
    }
    __syncthreads();
  }

  #pragma unroll
  for (int i=0;i<4;i++) {
    #pragma unroll
    for (int reg=0; reg<4; ++reg) {
      int m = m0 + wy*64 + i*16 + g4*4 + reg;
      if (m < ce) {
        int tok = tok_idx[e*NTOK + m] & (NTOK-1);
        float g = tok_gate[e*NTOK + m];
        #pragma unroll
        for (int j=0;j<4;j++) {
          int n = n0 + wx*64 + j*16 + r16;
          unsafeAtomicAdd(&out[(size_t)tok*D_ + n], g * acc[i][j][reg]);
        }
      }
    }
  }
}

// ---------------------------------------------------------------------------
__global__ void rope_table(const int* __restrict__ pos, float2* __restrict__ cs)
{
  int idx = blockIdx.x*256 + threadIdx.x;   // T*256
  int t = idx >> 8, j = idx & 255;
  float xj = (float)j * (1.0f/256.0f);
  float p32 = (float)pow(10000.0, (double)xj);
  float invf = 1.0f / p32;
  float ang = (float)pos[t] * invf;
  cs[idx] = make_float2(cosf(ang), sinf(ang));
}

// ---------------------------------------------------------------------------
// LN1 -> xn1 fp16 hi/lo planes + roped K planes (interleaved pair order)
// ---------------------------------------------------------------------------
__global__ void ln1_kernel(const float* __restrict__ x, const float* __restrict__ g,
    const float* __restrict__ be, const float2* __restrict__ cs,
    us* __restrict__ xn1h, us* __restrict__ xn1l,
    us* __restrict__ Krh, us* __restrict__ Krl)
{
  const int row = blockIdx.x;           // b*T + t
  const int t = row & (T_-1);
  const int tid = threadIdx.x;
  __shared__ float red[8];
  float v0 = x[(size_t)row*D_ + tid];
  float v1 = x[(size_t)row*D_ + 256 + tid];
  const int wid = tid>>6, lane = tid&63;
  float s = v0 + v1;
  #pragma unroll
  for (int m=1; m<64; m<<=1) s += __shfl_xor(s,m);
  if (lane == 0) red[wid] = s;
  __syncthreads();
  s = red[0]+red[1]+red[2]+red[3];
  float mu = s * (1.f/D_);
  float d0 = v0-mu, d1 = v1-mu;
  float q = d0*d0 + d1*d1;
  #pragma unroll
  for (int m=1; m<64; m<<=1) q += __shfl_xor(q,m);
  __syncthreads();
  if (lane == 0) red[wid] = q;
  __syncthreads();
  q = red[0]+red[1]+red[2]+red[3];
  float var = q * (1.f/D_);
  float rs = rsqrtf(var + 1e-5f);
  float n0 = d0*rs*g[tid]     + be[tid];
  float n1 = d1*rs*g[tid+256] + be[tid+256];
  splitf(n0, xn1h[(size_t)row*D_ + tid],       xn1l[(size_t)row*D_ + tid]);
  splitf(n1, xn1h[(size_t)row*D_ + 256 + tid], xn1l[(size_t)row*D_ + 256 + tid]);
  float2 c = cs[(size_t)t*256 + tid];
  float k0 = n0*c.x - n1*c.y;
  float k1 = n1*c.x + n0*c.y;
  us k0h,k0l,k1h,k1l;
  splitf(k0, k0h, k0l);
  splitf(k1, k1h, k1l);
  size_t kb = (size_t)row*D_ + 2*tid;
  *(unsigned*)(Krh + kb) = (unsigned)k0h | ((unsigned)k1h << 16);
  *(unsigned*)(Krl + kb) = (unsigned)k0l | ((unsigned)k1l << 16);
}

// ---------------------------------------------------------------------------
// Transpose-split both M (with RoPE pair permutation) and V in one launch.
// z=0: M -> Mth/Mtl (permuted rows); z=1: V -> Vth/Vtl.
// ---------------------------------------------------------------------------
__global__ void transpose_split2(const float* __restrict__ Mp, const float* __restrict__ Vp,
    us* __restrict__ Mth, us* __restrict__ Mtl,
    us* __restrict__ Vth, us* __restrict__ Vtl)
{
  const int zz = blockIdx.z;
  const float* in = zz ? Vp : Mp;
  us* outh = zz ? Vth : Mth;
  us* outl = zz ? Vtl : Mtl;
  const int R = D_, C = HD;
  __shared__ float tile[32][33];
  const int c0 = blockIdx.x*32, r0 = blockIdx.y*32;
  const int tc = threadIdx.x & 31, tr = threadIdx.x >> 5;  // tr in 0..7
  #pragma unroll
  for (int i=0;i<4;i++)
    tile[tr + 8*i][tc] = in[(size_t)(r0 + tr + 8*i)*C + c0 + tc];
  __syncthreads();
  #pragma unroll
  for (int i=0;i<4;i++) {
    float v = tile[tc][tr + 8*i];
    int j0 = c0 + tr + 8*i;
    int n = j0;
    if (!zz) {
      int jh = j0 & 511;
      n = (j0 & ~511) | ((jh & 255) << 1) | (jh >> 8);
    }
    size_t o = (size_t)n*R + r0 + tc;
    splitf(v, outh[o], outl[o]);
  }
}

// ---------------------------------------------------------------------------
// One-shot MoE weight cast: w1 -> w13b rows 2f, w3 -> rows 2f+1, w2 -> w2b.
// ---------------------------------------------------------------------------
__global__ void cast_moe(const float* __restrict__ w1, const float* __restrict__ w3,
    const float* __restrict__ w2, us* __restrict__ w13b, us* __restrict__ w2b)
{
  const int n1 = E_*F_*D_/4;
  int i = blockIdx.x*256 + threadIdx.x;   // 3*n1 total
  const float* src; int kind;
  int ii = i;
  if (i < n1)            { src = w1; kind = 0; }
  else if (i < 2*n1)     { src = w3; kind = 1; ii = i - n1; }
  else                   { src = w2; kind = 2; ii = i - 2*n1; }
  float4 v = ((const float4*)src)[ii];
  union { us u[4]; uint2 v2; } r;
  r.u[0]=f2b(v.x); r.u[1]=f2b(v.y); r.u[2]=f2b(v.z); r.u[3]=f2b(v.w);
  if (kind == 2) {
    ((uint2*)w2b)[ii] = r.v2;
  } else {
    int e = ii / (F_*D_/4);
    int rem = ii - e*(F_*D_/4);
    int f = rem / (D_/4);
    int d4 = rem - f*(D_/4);
    size_t ob = (size_t)e*(2*F_*D_/4) + (size_t)(2*f+kind)*(D_/4) + d4;
    ((uint2*)w13b)[ob] = r.v2;
  }
}

// ---------------------------------------------------------------------------
// x1 = x + Obsum; out = x1; xn2b = bf16(LN2(x1)); fused router logits (f32)
// ---------------------------------------------------------------------------
__global__ void resid_ln2_kernel(const float* __restrict__ x, const float* __restrict__ Obsum,
    const float* __restrict__ g, const float* __restrict__ be,
    const float* __restrict__ rw,
    float* __restrict__ out, us* __restrict__ xn2b, float* __restrict__ logits)
{
  const int row = blockIdx.x;
  const int tid = threadIdx.x;
  __shared__ float red[8];
  __shared__ float red2[4][8];
  float a0 = x[(size_t)row*D_ + tid]       + Obsum[(size_t)row*D_ + tid];
  float a1 = x[(size_t)row*D_ + 256 + tid] + Obsum[(size_t)row*D_ + 256 + tid];
  out[(size_t)row*D_ + tid] = a0;
  out[(size_t)row*D_ + 256 + tid] = a1;
  const int wid = tid>>6, lane = tid&63;
  float s = a0 + a1;
  #pragma unroll
  for (int m=1; m<64; m<<=1) s += __shfl_xor(s,m);
  if (lane == 0) red[wid] = s;
  __syncthreads();
  s = red[0]+red[1]+red[2]+red[3];
  float mu = s * (1.f/D_);
  float d0 = a0-mu, d1 = a1-mu;
  float q = d0*d0 + d1*d1;
  #pragma unroll
  for (int m=1; m<64; m<<=1) q += __shfl_xor(q,m);
  __syncthreads();
  if (lane == 0) red[wid] = q;
  __syncthreads();
  q = red[0]+red[1]+red[2]+red[3];
  float var = q * (1.f/D_);
  float rs = rsqrtf(var + 1e-5f);
  float n0 = d0*rs*g[tid]     + be[tid];
  float n1 = d1*rs*g[tid+256] + be[tid+256];
  xn2b[(size_t)row*D_ + tid]       = f2b(n0);
  xn2b[(size_t)row*D_ + 256 + tid] = f2b(n1);
  float pl[8];
  #pragma unroll
  for (int e=0;e<E_;e++)
    pl[e] = n0*rw[e*D_ + tid] + n1*rw[e*D_ + 256 + tid];
  #pragma unroll
  for (int m=1; m<64; m<<=1)
    #pragma unroll
    for (int e=0;e<E_;e++) pl[e] += __shfl_xor(pl[e], m);
  if (lane == 0)
    #pragma unroll
    for (int e=0;e<E_;e++) red2[wid][e] = pl[e];
  __syncthreads();
  if (tid < 8)
    logits[(size_t)row*8 + tid] = red2[0][tid]+red2[1][tid]+red2[2][tid]+red2[3][tid];
}

// ---------------------------------------------------------------------------
// Router compaction: single block, deterministic slot assignment.
// ---------------------------------------------------------------------------
__global__ __launch_bounds__(1024) void router_compact(
    const float* __restrict__ logits, int* __restrict__ cnt,
    int* __restrict__ tok_idx, float* __restrict__ tok_gate)
{
  const int tid = threadIdx.x;
  __shared__ int sc[1024][8];
  int e1v[4], e2v[4];
  float g1v[4], g2v[4];
  int lc[8] = {0,0,0,0,0,0,0,0};
  #pragma unroll
  for (int i=0;i<4;i++) {
    int tok = tid*4 + i;
    float lg[8];
    float4 a = *(const float4*)(logits + (size_t)tok*8);
    float4 b = *(const float4*)(logits + (size_t)tok*8 + 4);
    lg[0]=a.x; lg[1]=a.y; lg[2]=a.z; lg[3]=a.w;
    lg[4]=b.x; lg[5]=b.y; lg[6]=b.z; lg[7]=b.w;
    int i1 = 0;
    #pragma unroll
    for (int e=1;e<E_;e++) if (lg[e] > lg[i1]) i1 = e;
    int i2 = (i1==0) ? 1 : 0;
    #pragma unroll
    for (int e=0;e<E_;e++) if (e != i1 && lg[e] > lg[i2]) i2 = e;
    float p2 = expf(lg[i2] - lg[i1]);
    float den = 1.f + p2;
    e1v[i] = i1; g1v[i] = 1.f/den;
    e2v[i] = i2; g2v[i] = p2/den;
    lc[i1]++; lc[i2]++;
  }
  #pragma unroll
  for (int e=0;e<E_;e++) sc[tid][e] = lc[e];
  __syncthreads();
  for (int off=1; off<1024; off<<=1) {
    int tmp[8];
    if (tid >= off) {
      #pragma unroll
      for (int e=0;e<E_;e++) tmp[e] = sc[tid-off][e];
    }
    __syncthreads();
    if (tid >= off) {
      #pragma unroll
      for (int e=0;e<E_;e++) sc[tid][e] += tmp[e];
    }
    __syncthreads();
  }
  int run[8];
  #pragma unroll
  for (int e=0;e<E_;e++) run[e] = sc[tid][e] - lc[e];   // exclusive prefix
  if (tid == 0) {
    #pragma unroll
    for (int e=0;e<E_;e++) cnt[e] = sc[1023][e];
  }
  #pragma unroll
  for (int i=0;i<4;i++) {
    int tok = tid*4 + i;
    int s1 = run[e1v[i]]++;
    tok_idx[e1v[i]*NTOK + s1]  = tok;
    tok_gate[e1v[i]*NTOK + s1] = g1v[i];
    int s2 = run[e2v[i]]++;
    tok_idx[e2v[i]*NTOK + s2]  = tok;
    tok_gate[e2v[i]*NTOK + s2] = g2v[i];
  }
}

// ---------------------------------------------------------------------------
extern "C" void kernel_launch(void* const* d_in, const int* in_sizes, int n_in,
                              void* d_out, int out_size, void* d_ws, size_t ws_size,
                              hipStream_t stream)
{
  const float* x    = (const float*)d_in[0];
  const int*   pos  = (const int*)d_in[1];
  const float* ln1g = (const float*)d_in[2];
  const float* ln1b = (const float*)d_in[3];
  const float* M    = (const float*)d_in[4];
  const float* V    = (const float*)d_in[5];
  const float* ln2g = (const float*)d_in[6];
  const float* ln2b = (const float*)d_in[7];
  const float* rw   = (const float*)d_in[8];
  const float* w1   = (const float*)d_in[9];
  const float* w2   = (const float*)d_in[10];
  const float* w3   = (const float*)d_in[11];
  float* out = (float*)d_out;

  char* ws = (char*)d_ws;
  const size_t MB = (size_t)1 << 20;
  const bool merged = ws_size >= (size_t)229*MB;

  // --- persistent across attention phase ---
  float2* cs  = (float2*)(ws + 0);            // 2MB
  us* Krh  = (us*)(ws + 2*MB);                // 4MB (interleaved pair order)
  us* Krl  = (us*)(ws + 6*MB);                // 4MB
  us* valTh   = (us*)(ws + 10*MB);            // 32MB (10..42)
  us* valTl   = (us*)(ws + 42*MB);            // 32MB (42..74)
  us* Qhp     = (us*)(ws + 74*MB);            // 32MB (74..106)
  us* Qlp     = (us*)(ws + 106*MB);           // 32MB (106..138)
  float* S    = (float*)(ws + 138*MB);        // packed: 75.5MB (merged) / 18.9MB (per-batch)
  // projection-phase temporaries overlay the S region (dead before S written)
  us* xn1h = (us*)(ws + 138*MB);              // 4MB
  us* xn1l = (us*)(ws + 142*MB);              // 4MB
  us* Mth  = (us*)(ws + 146*MB);              // 8MB
  us* Mtl  = (us*)(ws + 154*MB);              // 8MB
  us* Vth  = (us*)(ws + 162*MB);              // 8MB
  us* Vtl  = (us*)(ws + 170*MB);              // 8MB (ends 178)
  // tail region: after S_all (merged) or at classic offsets (fallback)
  size_t tail = merged ? 214*MB : 180*MB;
  float* Obsum  = (float*)(ws + tail);                    // 8MB
  float* logits = (float*)(ws + tail + 8*MB);             // 128KB
  us*    xn2b   = (us*)   (ws + tail + 9*MB);             // 4MB
  int*   cnt      = (int*)  (ws + tail + 13*MB);          // 4KB
  int*   tok_idx  = (int*)  (ws + tail + 13*MB + 4096);   // 128KB
  float* tok_gate = (float*)(ws + tail + 13*MB + 4096 + 128*1024); // 128KB
  // MoE temporaries overlay attention-dead regions
  us* w13b = (us*)(ws + 10*MB);               // 16MB (over valT)
  us* w2b  = (us*)(ws + 26*MB);               // 8MB
  us* hb   = (us*)(ws + 74*MB);               // 64MB (over Q planes)

  hipMemsetAsync(Obsum, 0, (size_t)NTOK*D_*sizeof(float), stream);
  rope_table<<<T_, 256, 0, stream>>>(pos, cs);
  ln1_kernel<<<NTOK, 256, 0, stream>>>(x, ln1g, ln1b, cs, xn1h, xn1l, Krh, Krl);
  transpose_split2<<<dim3(HD/32, D_/32, 2), 256, 0, stream>>>(M, V, Mth, Mtl, Vth, Vtl);

  // Q = rope(xn1 @ M) fused epilogue -> Qhp/Qlp (interleaved pair order)
  gemm_ms<4><<<dim3(HD/128, NTOK/128, 1), 256, 0, stream>>>(
      xn1h, xn1l, Mth, Mtl, nullptr, Qhp, Qlp,
      NTOK, HD, D_, D_, D_, HD, cs, 0);
  // valT[h,d,b,t] = V^T @ xn1^T, split store
  gemm_ms<1><<<dim3(NTOK/128, HD/128, 1), 256, 0, stream>>>(
      Vth, Vtl, xn1h, xn1l, nullptr, valTh, valTl,
      HD, NTOK, D_, D_, D_, NTOK, nullptr, 0);

  // --- attention: packed causal S -> softmax -> PV ---
  if (merged) {
    gemm_ms<2><<<dim3(T_/128, T_/128, B_*H_), 256, 0, stream>>>(
        Qhp, Qlp, Krh, Krl, S, nullptr, nullptr,
        T_, T_, D_, HD, D_, 128, nullptr, 0);
    softmax_pk<<<B_*H_*T_, 256, 0, stream>>>(S);
    gemm_ms<5><<<dim3(D_/128, T_/128, B_*H_), 256, 0, stream>>>(
        (const us*)S, nullptr, valTh, valTl, Obsum, nullptr, nullptr,
        T_, D_, T_, 0, NTOK, D_, nullptr, 0);
  } else {
    for (int b = 0; b < B_; ++b) {
      gemm_ms<2><<<dim3(T_/128, T_/128, H_), 256, 0, stream>>>(
          Qhp, Qlp, Krh, Krl, S, nullptr, nullptr,
          T_, T_, D_, HD, D_, 128, nullptr, b);
      softmax_pk<<<H_*T_, 256, 0, stream>>>(S);
      gemm_ms<5><<<dim3(D_/128, T_/128, H_), 256, 0, stream>>>(
          (const us*)S, nullptr, valTh, valTl, Obsum, nullptr, nullptr,
          T_, D_, T_, 0, NTOK, D_, nullptr, b);
    }
  }

  resid_ln2_kernel<<<NTOK, 256, 0, stream>>>(x, Obsum, ln2g, ln2b, rw, out, xn2b, logits);
  router_compact<<<1, 1024, 0, stream>>>(logits, cnt, tok_idx, tok_gate);

  cast_moe<<<3*(E_*F_*D_/4)/256, 256, 0, stream>>>(w1, w3, w2, w13b, w2b);

  moe_w13<<<dim3(2*F_/128, NTOK/128, E_), 256, 0, stream>>>(
      xn2b, w13b, cnt, tok_idx, hb);
  moe_w2<<<dim3(D_/128, NTOK/128, E_), 256, 0, stream>>>(
      hb, w2b, cnt, tok_idx, tok_gate, out);
}